// Round 1
// baseline (3256.282 us; speedup 1.0000x reference)
//
#include <hip/hip_runtime.h>
#include <cstdint>
#include <cstddef>

// ---------------------------------------------------------------------------
// UniversalBehavioralTransformer — fp32 correctness-first implementation.
// B=8 N=1024 D=1024 H=8 DQK=DV=128 L=2. ~210 GFLOP fp32.
// Round-1 design notes:
//  - rab (pos_w + ts bucket) computed on the fly inside attention (cheap VALU).
//  - attention is flash-style tiled (64 q-rows x 32 k-rows), causal tile skip.
//  - GEMMs: 128x128 tile, BK=16, 8x8 microtile fp32 (swap to MFMA later).
//  - workspace: xb(32MB) + buf1(32MB) + buf2(32MB) + uvqk(128MB) + small.
// ---------------------------------------------------------------------------

#define BB   8
#define NNN  1024
#define DDD  1024
#define HHH  8
#define DVV  128
#define CCC  4096          // 2*H*DV + 2*H*DQK
#define TBK  128
#define INV_LOG2F 1.4426950408889634f

// ---------------- block reduce (works for blockDim 256 and 1024) -----------
__device__ __forceinline__ float block_reduce_sum(float v, float* sm) {
#pragma unroll
  for (int o = 32; o > 0; o >>= 1) v += __shfl_down(v, o, 64);
  int lane = threadIdx.x & 63;
  int wid  = threadIdx.x >> 6;
  __syncthreads();
  if (lane == 0) sm[wid] = v;
  __syncthreads();
  int nw = blockDim.x >> 6;
  float r = (threadIdx.x < nw) ? sm[threadIdx.x] : 0.f;
#pragma unroll
  for (int o = 8; o > 0; o >>= 1) r += __shfl_down(r, o, 64);
  if (threadIdx.x == 0) sm[0] = r;
  __syncthreads();
  return sm[0];
}

// ---------------- x = x * mask ---------------------------------------------
__global__ __launch_bounds__(256) void mask_x_k(const float* __restrict__ x,
                                                const float* __restrict__ mask,
                                                float* __restrict__ xb) {
  size_t i4 = (size_t)blockIdx.x * 256 + threadIdx.x;   // float4 index
  size_t row = i4 >> 8;                                  // (b*N+n), 256 float4/row
  float m = mask[row];
  float4 v = ((const float4*)x)[i4];
  v.x *= m; v.y *= m; v.z *= m; v.w *= m;
  ((float4*)xb)[i4] = v;
}

// ---------------- LayerNorm (optionally * u) -------------------------------
// one block (256 thr) per row of 1024; two-pass (mean, then var) like ref.
__global__ __launch_bounds__(256) void ln_k(const float* __restrict__ X,
                                            const float* __restrict__ g,
                                            const float* __restrict__ bsh,
                                            const float* __restrict__ umat,
                                            int ustride,
                                            float* __restrict__ Y) {
  __shared__ float sm[16];
  size_t row = blockIdx.x;
  const float* xr = X + row * DDD;
  int d = threadIdx.x * 4;
  float4 xv = *(const float4*)(xr + d);
  float s = xv.x + xv.y + xv.z + xv.w;
  s = block_reduce_sum(s, sm);
  float mu = s * (1.f / 1024.f);
  float d0 = xv.x - mu, d1 = xv.y - mu, d2 = xv.z - mu, d3 = xv.w - mu;
  float ss = d0 * d0 + d1 * d1 + d2 * d2 + d3 * d3;
  ss = block_reduce_sum(ss, sm);
  float rs = rsqrtf(ss * (1.f / 1024.f) + 1e-6f);
  float4 yv;
  yv.x = d0 * rs * g[d + 0] + bsh[d + 0];
  yv.y = d1 * rs * g[d + 1] + bsh[d + 1];
  yv.z = d2 * rs * g[d + 2] + bsh[d + 2];
  yv.w = d3 * rs * g[d + 3] + bsh[d + 3];
  if (umat != nullptr) {
    const float* ur = umat + row * (size_t)ustride + d;
    yv.x *= ur[0]; yv.y *= ur[1]; yv.z *= ur[2]; yv.w *= ur[3];
  }
  *(float4*)(Y + row * DDD + d) = yv;
}

// ---------------- fp32 GEMM: C = epilogue(A[MxK] @ W[KxNn] + bias) ----------
// MODE 0: C = silu(z).  MODE 1: C += z (residual accumulate).
// 256 threads, 128x128 tile, BK=16, 8x8 microtile.
template <int MODE>
__global__ __launch_bounds__(256) void gemm_k(const float* __restrict__ A,
                                              const float* __restrict__ W,
                                              const float* __restrict__ bias,
                                              float* __restrict__ C,
                                              int M, int K, int Nn) {
  __shared__ float As[16][132];
  __shared__ float Ws[16][132];
  int tid = threadIdx.x;
  int tx = tid & 15, ty = tid >> 4;
  int m0 = blockIdx.y * 128, n0 = blockIdx.x * 128;

  int ar = tid >> 2, aseg = tid & 3;     // A tile: rows ar, ar+64; cols aseg*4..+3
  int wr = tid >> 5, wseg = tid & 31;    // W tile: rows wr, wr+8; cols wseg*4..+3

  float acc[8][8] = {};

  for (int k0 = 0; k0 < K; k0 += 16) {
    float4 a0 = *(const float4*)(A + (size_t)(m0 + ar) * K + k0 + aseg * 4);
    float4 a1 = *(const float4*)(A + (size_t)(m0 + ar + 64) * K + k0 + aseg * 4);
    float4 w0 = *(const float4*)(W + (size_t)(k0 + wr) * Nn + n0 + wseg * 4);
    float4 w1 = *(const float4*)(W + (size_t)(k0 + wr + 8) * Nn + n0 + wseg * 4);
    __syncthreads();
    As[aseg * 4 + 0][ar] = a0.x; As[aseg * 4 + 1][ar] = a0.y;
    As[aseg * 4 + 2][ar] = a0.z; As[aseg * 4 + 3][ar] = a0.w;
    As[aseg * 4 + 0][ar + 64] = a1.x; As[aseg * 4 + 1][ar + 64] = a1.y;
    As[aseg * 4 + 2][ar + 64] = a1.z; As[aseg * 4 + 3][ar + 64] = a1.w;
    *(float4*)&Ws[wr][wseg * 4] = w0;
    *(float4*)&Ws[wr + 8][wseg * 4] = w1;
    __syncthreads();
#pragma unroll
    for (int k = 0; k < 16; ++k) {
      float a[8], b[8];
      *(float4*)(a)     = *(const float4*)&As[k][ty * 8];
      *(float4*)(a + 4) = *(const float4*)&As[k][ty * 8 + 4];
      *(float4*)(b)     = *(const float4*)&Ws[k][tx * 8];
      *(float4*)(b + 4) = *(const float4*)&Ws[k][tx * 8 + 4];
#pragma unroll
      for (int i = 0; i < 8; ++i)
#pragma unroll
        for (int j = 0; j < 8; ++j) acc[i][j] += a[i] * b[j];
    }
  }

  float bs[8];
#pragma unroll
  for (int j = 0; j < 8; ++j) bs[j] = bias[n0 + tx * 8 + j];

#pragma unroll
  for (int i = 0; i < 8; ++i) {
    int row = m0 + ty * 8 + i;
    float* crow = C + (size_t)row * Nn + n0 + tx * 8;
    if (MODE == 0) {
      float4 o0, o1;
      float z;
      z = acc[i][0] + bs[0]; o0.x = z / (1.f + __expf(-z));
      z = acc[i][1] + bs[1]; o0.y = z / (1.f + __expf(-z));
      z = acc[i][2] + bs[2]; o0.z = z / (1.f + __expf(-z));
      z = acc[i][3] + bs[3]; o0.w = z / (1.f + __expf(-z));
      z = acc[i][4] + bs[4]; o1.x = z / (1.f + __expf(-z));
      z = acc[i][5] + bs[5]; o1.y = z / (1.f + __expf(-z));
      z = acc[i][6] + bs[6]; o1.z = z / (1.f + __expf(-z));
      z = acc[i][7] + bs[7]; o1.w = z / (1.f + __expf(-z));
      *(float4*)crow = o0;
      *(float4*)(crow + 4) = o1;
    } else {
      float4 c0 = *(const float4*)crow;
      float4 c1 = *(const float4*)(crow + 4);
      c0.x += acc[i][0] + bs[0]; c0.y += acc[i][1] + bs[1];
      c0.z += acc[i][2] + bs[2]; c0.w += acc[i][3] + bs[3];
      c1.x += acc[i][4] + bs[4]; c1.y += acc[i][5] + bs[5];
      c1.z += acc[i][6] + bs[6]; c1.w += acc[i][7] + bs[7];
      *(float4*)crow = c0;
      *(float4*)(crow + 4) = c1;
    }
  }
}

// ---------------- fused attention ------------------------------------------
// o[b,n,h*128+dv] = sum_m silu(q.k + rab(b,n,m))/N * tril * mask[b,m] * v
// grid (N/64, H, B), 256 threads. Tiles: 64 q-rows x 32 k-rows.
__global__ __launch_bounds__(256) void attn_k(const float* __restrict__ uvqk,
                                              const int* __restrict__ ts,
                                              const float* __restrict__ mask,
                                              const float* __restrict__ pos_w,
                                              const float* __restrict__ ts_w,
                                              float* __restrict__ o) {
  __shared__ float Qs[64][132];
  __shared__ float Ks[32][132];
  __shared__ float Vs[32][132];
  __shared__ float Ps[64][33];
  __shared__ int tsQ[64];
  __shared__ int tsK[32];

  int n0 = blockIdx.x * 64;
  int h  = blockIdx.y;
  int b  = blockIdx.z;
  int tid = threadIdx.x;
  int tx = tid & 15, ty = tid >> 4;

  const float* qbase = uvqk + ((size_t)(b * NNN + n0)) * CCC + 2048 + h * 128;
  const float* kbase = uvqk + (size_t)b * NNN * CCC + 3072 + h * 128;
  const float* vbase = uvqk + (size_t)b * NNN * CCC + 1024 + h * 128;

  {  // load Q tile 64x128
    int seg = tid & 31, r0 = tid >> 5;
#pragma unroll
    for (int rr = 0; rr < 8; ++rr) {
      int row = r0 + rr * 8;
      *(float4*)&Qs[row][seg * 4] =
          *(const float4*)(qbase + (size_t)row * CCC + seg * 4);
    }
  }
  if (tid < 64) {
    int ii = n0 + tid + 1; if (ii > NNN - 1) ii = NNN - 1;   // ext[:,1:]
    tsQ[tid] = ts[(size_t)b * NNN + ii];
  }

  float Oacc[4][8] = {};
  int mtiles = (n0 + 63) / 32 + 1;   // causal: only tiles with m0 <= n_end

  for (int mt = 0; mt < mtiles; ++mt) {
    int m0 = mt * 32;
    __syncthreads();   // protect Ks/Vs/Ps reuse across iterations
    {
      int seg = tid & 31, r0 = tid >> 5;
#pragma unroll
      for (int rr = 0; rr < 4; ++rr) {
        int row = r0 + rr * 8;
        *(float4*)&Ks[row][seg * 4] =
            *(const float4*)(kbase + (size_t)(m0 + row) * CCC + seg * 4);
        *(float4*)&Vs[row][seg * 4] =
            *(const float4*)(vbase + (size_t)(m0 + row) * CCC + seg * 4);
      }
    }
    if (tid < 32) tsK[tid] = ts[(size_t)b * NNN + m0 + tid];
    __syncthreads();

    // S: rows ty*4..+3, cols tx*2..+1 (dot length 128)
    float S[4][2] = {};
    for (int kk = 0; kk < 128; kk += 4) {
      float4 q[4], kv[2];
#pragma unroll
      for (int i = 0; i < 4; ++i) q[i] = *(const float4*)&Qs[ty * 4 + i][kk];
#pragma unroll
      for (int j = 0; j < 2; ++j) kv[j] = *(const float4*)&Ks[tx * 2 + j][kk];
#pragma unroll
      for (int i = 0; i < 4; ++i)
#pragma unroll
        for (int j = 0; j < 2; ++j)
          S[i][j] += q[i].x * kv[j].x + q[i].y * kv[j].y +
                     q[i].z * kv[j].z + q[i].w * kv[j].w;
    }

    // P = silu(S + rab)/N * (j<=i) * mask[b,j]
#pragma unroll
    for (int i = 0; i < 4; ++i) {
      int gi = n0 + ty * 4 + i;
      int ti = tsQ[ty * 4 + i];
#pragma unroll
      for (int j = 0; j < 2; ++j) {
        int gj = m0 + tx * 2 + j;
        float mval = (gj <= gi) ? mask[(size_t)b * NNN + gj] : 0.f;
        int dlt = ti - tsK[tx * 2 + j];
        float af = fabsf((float)dlt);
        if (af < 1.f) af = 1.f;
        int bkt = (int)(__logf(af) * INV_LOG2F);
        if (bkt < 0) bkt = 0;
        if (bkt > TBK) bkt = TBK;
        float rab = pos_w[gi - gj + NNN - 1] + ts_w[bkt];
        float z = S[i][j] + rab;
        float p = (z / (1.f + __expf(-z))) * (1.f / (float)NNN) * mval;
        Ps[ty * 4 + i][tx * 2 + j] = p;
      }
    }
    __syncthreads();

    // O[rows ty*4..+3][cols tx*8..+7] += P @ V
    for (int m = 0; m < 32; ++m) {
      float4 v0 = *(const float4*)&Vs[m][tx * 8];
      float4 v1 = *(const float4*)&Vs[m][tx * 8 + 4];
#pragma unroll
      for (int i = 0; i < 4; ++i) {
        float p = Ps[ty * 4 + i][m];
        Oacc[i][0] += p * v0.x; Oacc[i][1] += p * v0.y;
        Oacc[i][2] += p * v0.z; Oacc[i][3] += p * v0.w;
        Oacc[i][4] += p * v1.x; Oacc[i][5] += p * v1.y;
        Oacc[i][6] += p * v1.z; Oacc[i][7] += p * v1.w;
      }
    }
  }

#pragma unroll
  for (int i = 0; i < 4; ++i) {
    float* orow = o + ((size_t)(b * NNN + n0 + ty * 4 + i)) * DDD + h * 128 + tx * 8;
    float4 o0, o1;
    o0.x = Oacc[i][0]; o0.y = Oacc[i][1]; o0.z = Oacc[i][2]; o0.w = Oacc[i][3];
    o1.x = Oacc[i][4]; o1.y = Oacc[i][5]; o1.z = Oacc[i][6]; o1.w = Oacc[i][7];
    *(float4*)orow = o0;
    *(float4*)(orow + 4) = o1;
  }
}

// ---------------- pooling ---------------------------------------------------
__global__ __launch_bounds__(256) void row_stats_k(const float* __restrict__ xb,
                                                   float* __restrict__ invn) {
  __shared__ float sm[16];
  size_t row = blockIdx.x;
  int d = threadIdx.x * 4;
  float4 xv = *(const float4*)(xb + row * DDD + d);
  float ss = xv.x * xv.x + xv.y * xv.y + xv.z * xv.z + xv.w * xv.w;
  ss = block_reduce_sum(ss, sm);
  if (threadIdx.x == 0) invn[row] = 1.f / fmaxf(sqrtf(ss), 1e-12f);
}

__global__ __launch_bounds__(1024) void pool_partial_k(const float* __restrict__ xb,
                                                       const float* __restrict__ mask,
                                                       const float* __restrict__ invn,
                                                       float* __restrict__ partial) {
  int b = blockIdx.x, c = blockIdx.y, d = threadIdx.x;
  float s = 0.f;
  int nbeg = c * 64;
  for (int n = nbeg; n < nbeg + 64; ++n) {
    size_t r = (size_t)b * NNN + n;
    s += xb[r * DDD + d] * mask[r] * invn[r];
  }
  partial[((size_t)b * 16 + c) * DDD + d] = s;
}

__global__ __launch_bounds__(1024) void pool_final_k(const float* __restrict__ xb,
                                                     const float* __restrict__ mask,
                                                     const float* __restrict__ invn,
                                                     const float* __restrict__ partial,
                                                     float* __restrict__ out) {
  __shared__ float sm[16];
  int b = blockIdx.x, d = threadIdx.x;
  float msum = mask[(size_t)b * NNN + d];
  msum = block_reduce_sum(msum, sm);
  int len = (int)(msum + 0.5f);
  float s = 0.f;
#pragma unroll
  for (int c = 0; c < 16; ++c) s += partial[((size_t)b * 16 + c) * DDD + d];
  float avg = s / (float)len;
  size_t lr = (size_t)b * NNN + (len - 1);
  float last = xb[lr * DDD + d] * invn[lr];
  float pooled = 0.5f * (last + avg);
  float ssq = block_reduce_sum(pooled * pooled, sm);
  out[(size_t)b * DDD + d] = pooled / fmaxf(sqrtf(ssq), 1e-12f);
}

// ---------------- launch ----------------------------------------------------
extern "C" void kernel_launch(void* const* d_in, const int* in_sizes, int n_in,
                              void* d_out, int out_size, void* d_ws, size_t ws_size,
                              hipStream_t stream) {
  const float* x      = (const float*)d_in[0];
  const int*   ts     = (const int*)d_in[1];   // jnp int64 w/o x64 => int32
  const float* mask   = (const float*)d_in[2];
  const float* ln1_g  = (const float*)d_in[3];
  const float* ln1_b  = (const float*)d_in[4];
  const float* w_uvqk = (const float*)d_in[5];
  const float* b_uvqk = (const float*)d_in[6];
  const float* ln2_g  = (const float*)d_in[7];
  const float* ln2_b  = (const float*)d_in[8];
  const float* w_o    = (const float*)d_in[9];
  const float* b_o    = (const float*)d_in[10];
  const float* pos_w  = (const float*)d_in[11];
  const float* ts_w   = (const float*)d_in[12];
  float* out = (float*)d_out;

  float* ws = (float*)d_ws;
  const size_t SZ = (size_t)BB * NNN * DDD;       // 8M floats
  float* xb    = ws;
  float* buf1  = ws + SZ;                          // h, then o
  float* buf2  = ws + 2 * SZ;                      // a = LN2(o)*u
  float* uvqk  = ws + 3 * SZ;                      // 32M floats
  float* invn  = ws + 3 * SZ + (size_t)BB * NNN * CCC;
  float* partial = invn + (size_t)BB * NNN;

  // x = x * mask
  mask_x_k<<<(BB * NNN * DDD / 4) / 256, 256, 0, stream>>>(x, mask, xb);

  for (int l = 0; l < 2; ++l) {
    // h = LN1(x)
    ln_k<<<BB * NNN, 256, 0, stream>>>(xb, ln1_g + l * DDD, ln1_b + l * DDD,
                                       nullptr, 0, buf1);
    // uvqk = silu(h @ w_uvqk + b_uvqk)
    gemm_k<0><<<dim3(CCC / 128, BB * NNN / 128), 256, 0, stream>>>(
        buf1, w_uvqk + (size_t)l * DDD * CCC, b_uvqk + (size_t)l * CCC, uvqk,
        BB * NNN, DDD, CCC);
    // o = attention(q,k,v,rab)  -> buf1 (h is dead)
    attn_k<<<dim3(NNN / 64, HHH, BB), 256, 0, stream>>>(uvqk, ts, mask, pos_w,
                                                        ts_w, buf1);
    // a = LN2(o) * u  -> buf2   (u is uvqk[..., :1024], stride 4096)
    ln_k<<<BB * NNN, 256, 0, stream>>>(buf1, ln2_g + l * DDD, ln2_b + l * DDD,
                                       uvqk, CCC, buf2);
    // x += a @ w_o + b_o
    gemm_k<1><<<dim3(DDD / 128, BB * NNN / 128), 256, 0, stream>>>(
        buf2, w_o + (size_t)l * DDD * DDD, b_o + (size_t)l * DDD, xb,
        BB * NNN, DDD, DDD);
  }

  // pooling
  row_stats_k<<<BB * NNN, 256, 0, stream>>>(xb, invn);
  pool_partial_k<<<dim3(BB, 16), 1024, 0, stream>>>(xb, mask, invn, partial);
  pool_final_k<<<BB, 1024, 0, stream>>>(xb, mask, invn, partial, out);
}

// Round 2
// 1828.050 us; speedup vs baseline: 1.7813x; 1.7813x over previous
//
#include <hip/hip_runtime.h>
#include <hip/hip_bf16.h>
#include <cstdint>
#include <cstddef>

// ---------------------------------------------------------------------------
// Round 2: bf16-MFMA GEMMs (m97 structure: global_load_lds width=16, 128x128
// tile, BK=32, 16x16x32 bf16 MFMA, swizzled global->LDS so frag ds_read_b128
// is conflict-free). Attention / residual / uvqk remain fp32.
// ---------------------------------------------------------------------------

#define BB   8
#define NNN  1024
#define DDD  1024
#define HHH  8
#define DVV  128
#define CCC  4096
#define TBK  128
#define INV_LOG2F 1.4426950408889634f

typedef __bf16 bf8_t  __attribute__((ext_vector_type(8)));
typedef float  f4_t   __attribute__((ext_vector_type(4)));

// ---------------- block reduce ---------------------------------------------
__device__ __forceinline__ float block_reduce_sum(float v, float* sm) {
#pragma unroll
  for (int o = 32; o > 0; o >>= 1) v += __shfl_down(v, o, 64);
  int lane = threadIdx.x & 63;
  int wid  = threadIdx.x >> 6;
  __syncthreads();
  if (lane == 0) sm[wid] = v;
  __syncthreads();
  int nw = blockDim.x >> 6;
  float r = (threadIdx.x < nw) ? sm[threadIdx.x] : 0.f;
#pragma unroll
  for (int o = 8; o > 0; o >>= 1) r += __shfl_down(r, o, 64);
  if (threadIdx.x == 0) sm[0] = r;
  __syncthreads();
  return sm[0];
}

// ---------------- x = x * mask ---------------------------------------------
__global__ __launch_bounds__(256) void mask_x_k(const float* __restrict__ x,
                                                const float* __restrict__ mask,
                                                float* __restrict__ xb) {
  size_t i4 = (size_t)blockIdx.x * 256 + threadIdx.x;
  size_t row = i4 >> 8;
  float m = mask[row];
  float4 v = ((const float4*)x)[i4];
  v.x *= m; v.y *= m; v.z *= m; v.w *= m;
  ((float4*)xb)[i4] = v;
}

// ---------------- weight transpose + bf16 convert ---------------------------
// W[K][Nn] fp32 -> Wt[Nn][K] bf16.  grid (K/32, Nn/32), 256 thr.
__global__ __launch_bounds__(256) void wconv_k(const float* __restrict__ W,
                                               __hip_bfloat16* __restrict__ Wt,
                                               int K, int Nn) {
  __shared__ float t[32][33];
  int k0 = blockIdx.x * 32, n0 = blockIdx.y * 32;
  int tx = threadIdx.x & 31, ty = threadIdx.x >> 5;
  for (int r = ty; r < 32; r += 8)
    t[r][tx] = W[(size_t)(k0 + r) * Nn + n0 + tx];
  __syncthreads();
  for (int r = ty; r < 32; r += 8)
    Wt[(size_t)(n0 + r) * K + k0 + tx] = __float2bfloat16(t[tx][r]);
}

// ---------------- LayerNorm (optionally * u), bf16 output -------------------
__global__ __launch_bounds__(256) void ln_k(const float* __restrict__ X,
                                            const float* __restrict__ g,
                                            const float* __restrict__ bsh,
                                            const float* __restrict__ umat,
                                            int ustride,
                                            __hip_bfloat16* __restrict__ Y) {
  __shared__ float sm[16];
  size_t row = blockIdx.x;
  const float* xr = X + row * DDD;
  int d = threadIdx.x * 4;
  float4 xv = *(const float4*)(xr + d);
  float s = xv.x + xv.y + xv.z + xv.w;
  s = block_reduce_sum(s, sm);
  float mu = s * (1.f / 1024.f);
  float d0 = xv.x - mu, d1 = xv.y - mu, d2 = xv.z - mu, d3 = xv.w - mu;
  float ss = d0 * d0 + d1 * d1 + d2 * d2 + d3 * d3;
  ss = block_reduce_sum(ss, sm);
  float rs = rsqrtf(ss * (1.f / 1024.f) + 1e-6f);
  float y0 = d0 * rs * g[d + 0] + bsh[d + 0];
  float y1 = d1 * rs * g[d + 1] + bsh[d + 1];
  float y2 = d2 * rs * g[d + 2] + bsh[d + 2];
  float y3 = d3 * rs * g[d + 3] + bsh[d + 3];
  if (umat != nullptr) {
    const float* ur = umat + row * (size_t)ustride + d;
    y0 *= ur[0]; y1 *= ur[1]; y2 *= ur[2]; y3 *= ur[3];
  }
  __hip_bfloat16 tmp[4];
  tmp[0] = __float2bfloat16(y0); tmp[1] = __float2bfloat16(y1);
  tmp[2] = __float2bfloat16(y2); tmp[3] = __float2bfloat16(y3);
  *(uint2*)(Y + row * DDD + d) = *(uint2*)tmp;
}

// ---------------- bf16 MFMA GEMM -------------------------------------------
// C[M][Nn](fp32) = epi(Abf[M][K](bf16) @ Bt[Nn][K](bf16)^T + bias)
// MODE 0: silu.  MODE 1: C += z (+bias).
// 256 thr = 4 waves (2x2), per-wave 64x64 = 4x4 of 16x16x32 MFMA. BK=32.
// Staging: global_load_lds 16B/lane, swizzled source so that stored 16B-chunk
// position p of row r holds k-chunk q with p=(q+(r>>1))&3 -> frag reads are
// <=2-way bank-aliased (free).
template <int MODE>
__global__ __launch_bounds__(256) void gemm_bf_k(const ushort* __restrict__ A,
                                                 const ushort* __restrict__ Bt,
                                                 const float* __restrict__ bias,
                                                 float* __restrict__ C,
                                                 int K, int Nn) {
  __shared__ alignas(16) ushort As[128 * 32];
  __shared__ alignas(16) ushort Bs[128 * 32];
  int tid = threadIdx.x;
  int wave = tid >> 6, lane = tid & 63;
  int quad = lane >> 4, l16 = lane & 15;
  int wm = wave >> 1, wn = wave & 1;
  int m0 = blockIdx.y * 128, n0 = blockIdx.x * 128;

  f4_t acc[4][4] = {};

  int r_l = tid >> 2;      // 0..63 (row within 64-row group)
  int p   = tid & 3;       // 16B chunk position within row

  for (int k0 = 0; k0 < K; k0 += 32) {
    __syncthreads();                       // prior frag reads done
#pragma unroll
    for (int g = 0; g < 2; ++g) {
      int row = g * 64 + r_l;
      int q = (p - (row >> 1)) & 3;        // k-chunk stored at position p
      __builtin_amdgcn_global_load_lds(
          (const __attribute__((address_space(1))) void*)(A + (size_t)(m0 + row) * K + k0 + q * 8),
          (__attribute__((address_space(3))) void*)(As + (g * 64 + wave * 16) * 32),
          16, 0, 0);
      __builtin_amdgcn_global_load_lds(
          (const __attribute__((address_space(1))) void*)(Bt + (size_t)(n0 + row) * K + k0 + q * 8),
          (__attribute__((address_space(3))) void*)(Bs + (g * 64 + wave * 16) * 32),
          16, 0, 0);
    }
    __syncthreads();                       // drains vmcnt before barrier

    bf8_t af[4], bfr[4];
#pragma unroll
    for (int t = 0; t < 4; ++t) {
      int row = wm * 64 + t * 16 + l16;
      af[t] = *(const bf8_t*)&As[row * 32 + ((quad + (row >> 1)) & 3) * 8];
      int col = wn * 64 + t * 16 + l16;
      bfr[t] = *(const bf8_t*)&Bs[col * 32 + ((quad + (col >> 1)) & 3) * 8];
    }
#pragma unroll
    for (int i = 0; i < 4; ++i)
#pragma unroll
      for (int j = 0; j < 4; ++j)
        acc[i][j] = __builtin_amdgcn_mfma_f32_16x16x32_bf16(af[i], bfr[j],
                                                            acc[i][j], 0, 0, 0);
  }

  // epilogue: D layout col=lane&15, row=quad*4+reg
#pragma unroll
  for (int j = 0; j < 4; ++j) {
    int col = n0 + wn * 64 + j * 16 + l16;
    float bz = bias[col];
#pragma unroll
    for (int i = 0; i < 4; ++i) {
      int rbase = m0 + wm * 64 + i * 16 + quad * 4;
#pragma unroll
      for (int r = 0; r < 4; ++r) {
        float z = acc[i][j][r] + bz;
        float* cp = C + (size_t)(rbase + r) * Nn + col;
        if (MODE == 0) {
          *cp = z / (1.f + __expf(-z));
        } else {
          *cp += z;
        }
      }
    }
  }
}

// ---------------- fused attention (fp32, unchanged) -------------------------
__global__ __launch_bounds__(256) void attn_k(const float* __restrict__ uvqk,
                                              const int* __restrict__ ts,
                                              const float* __restrict__ mask,
                                              const float* __restrict__ pos_w,
                                              const float* __restrict__ ts_w,
                                              float* __restrict__ o) {
  __shared__ float Qs[64][132];
  __shared__ float Ks[32][132];
  __shared__ float Vs[32][132];
  __shared__ float Ps[64][33];
  __shared__ int tsQ[64];
  __shared__ int tsK[32];

  int n0 = blockIdx.x * 64;
  int h  = blockIdx.y;
  int b  = blockIdx.z;
  int tid = threadIdx.x;
  int tx = tid & 15, ty = tid >> 4;

  const float* qbase = uvqk + ((size_t)(b * NNN + n0)) * CCC + 2048 + h * 128;
  const float* kbase = uvqk + (size_t)b * NNN * CCC + 3072 + h * 128;
  const float* vbase = uvqk + (size_t)b * NNN * CCC + 1024 + h * 128;

  {
    int seg = tid & 31, r0 = tid >> 5;
#pragma unroll
    for (int rr = 0; rr < 8; ++rr) {
      int row = r0 + rr * 8;
      *(float4*)&Qs[row][seg * 4] =
          *(const float4*)(qbase + (size_t)row * CCC + seg * 4);
    }
  }
  if (tid < 64) {
    int ii = n0 + tid + 1; if (ii > NNN - 1) ii = NNN - 1;
    tsQ[tid] = ts[(size_t)b * NNN + ii];
  }

  float Oacc[4][8] = {};
  int mtiles = (n0 + 63) / 32 + 1;

  for (int mt = 0; mt < mtiles; ++mt) {
    int m0 = mt * 32;
    __syncthreads();
    {
      int seg = tid & 31, r0 = tid >> 5;
#pragma unroll
      for (int rr = 0; rr < 4; ++rr) {
        int row = r0 + rr * 8;
        *(float4*)&Ks[row][seg * 4] =
            *(const float4*)(kbase + (size_t)(m0 + row) * CCC + seg * 4);
        *(float4*)&Vs[row][seg * 4] =
            *(const float4*)(vbase + (size_t)(m0 + row) * CCC + seg * 4);
      }
    }
    if (tid < 32) tsK[tid] = ts[(size_t)b * NNN + m0 + tid];
    __syncthreads();

    float S[4][2] = {};
    for (int kk = 0; kk < 128; kk += 4) {
      float4 q[4], kv[2];
#pragma unroll
      for (int i = 0; i < 4; ++i) q[i] = *(const float4*)&Qs[ty * 4 + i][kk];
#pragma unroll
      for (int j = 0; j < 2; ++j) kv[j] = *(const float4*)&Ks[tx * 2 + j][kk];
#pragma unroll
      for (int i = 0; i < 4; ++i)
#pragma unroll
        for (int j = 0; j < 2; ++j)
          S[i][j] += q[i].x * kv[j].x + q[i].y * kv[j].y +
                     q[i].z * kv[j].z + q[i].w * kv[j].w;
    }

#pragma unroll
    for (int i = 0; i < 4; ++i) {
      int gi = n0 + ty * 4 + i;
      int ti = tsQ[ty * 4 + i];
#pragma unroll
      for (int j = 0; j < 2; ++j) {
        int gj = m0 + tx * 2 + j;
        float mval = (gj <= gi) ? mask[(size_t)b * NNN + gj] : 0.f;
        int dlt = ti - tsK[tx * 2 + j];
        float af = fabsf((float)dlt);
        if (af < 1.f) af = 1.f;
        int bkt = (int)(__logf(af) * INV_LOG2F);
        if (bkt < 0) bkt = 0;
        if (bkt > TBK) bkt = TBK;
        float rab = pos_w[gi - gj + NNN - 1] + ts_w[bkt];
        float z = S[i][j] + rab;
        float pv = (z / (1.f + __expf(-z))) * (1.f / (float)NNN) * mval;
        Ps[ty * 4 + i][tx * 2 + j] = pv;
      }
    }
    __syncthreads();

    for (int m = 0; m < 32; ++m) {
      float4 v0 = *(const float4*)&Vs[m][tx * 8];
      float4 v1 = *(const float4*)&Vs[m][tx * 8 + 4];
#pragma unroll
      for (int i = 0; i < 4; ++i) {
        float pp = Ps[ty * 4 + i][m];
        Oacc[i][0] += pp * v0.x; Oacc[i][1] += pp * v0.y;
        Oacc[i][2] += pp * v0.z; Oacc[i][3] += pp * v0.w;
        Oacc[i][4] += pp * v1.x; Oacc[i][5] += pp * v1.y;
        Oacc[i][6] += pp * v1.z; Oacc[i][7] += pp * v1.w;
      }
    }
  }

#pragma unroll
  for (int i = 0; i < 4; ++i) {
    float* orow = o + ((size_t)(b * NNN + n0 + ty * 4 + i)) * DDD + h * 128 + tx * 8;
    float4 o0, o1;
    o0.x = Oacc[i][0]; o0.y = Oacc[i][1]; o0.z = Oacc[i][2]; o0.w = Oacc[i][3];
    o1.x = Oacc[i][4]; o1.y = Oacc[i][5]; o1.z = Oacc[i][6]; o1.w = Oacc[i][7];
    *(float4*)orow = o0;
    *(float4*)(orow + 4) = o1;
  }
}

// ---------------- pooling ---------------------------------------------------
__global__ __launch_bounds__(256) void row_stats_k(const float* __restrict__ xb,
                                                   float* __restrict__ invn) {
  __shared__ float sm[16];
  size_t row = blockIdx.x;
  int d = threadIdx.x * 4;
  float4 xv = *(const float4*)(xb + row * DDD + d);
  float ss = xv.x * xv.x + xv.y * xv.y + xv.z * xv.z + xv.w * xv.w;
  ss = block_reduce_sum(ss, sm);
  if (threadIdx.x == 0) invn[row] = 1.f / fmaxf(sqrtf(ss), 1e-12f);
}

__global__ __launch_bounds__(1024) void pool_partial_k(const float* __restrict__ xb,
                                                       const float* __restrict__ mask,
                                                       const float* __restrict__ invn,
                                                       float* __restrict__ partial) {
  int b = blockIdx.x, c = blockIdx.y, d = threadIdx.x;
  float s = 0.f;
  int nbeg = c * 64;
  for (int n = nbeg; n < nbeg + 64; ++n) {
    size_t r = (size_t)b * NNN + n;
    s += xb[r * DDD + d] * mask[r] * invn[r];
  }
  partial[((size_t)b * 16 + c) * DDD + d] = s;
}

__global__ __launch_bounds__(1024) void pool_final_k(const float* __restrict__ xb,
                                                     const float* __restrict__ mask,
                                                     const float* __restrict__ invn,
                                                     const float* __restrict__ partial,
                                                     float* __restrict__ out) {
  __shared__ float sm[16];
  int b = blockIdx.x, d = threadIdx.x;
  float msum = mask[(size_t)b * NNN + d];
  msum = block_reduce_sum(msum, sm);
  int len = (int)(msum + 0.5f);
  float s = 0.f;
#pragma unroll
  for (int c = 0; c < 16; ++c) s += partial[((size_t)b * 16 + c) * DDD + d];
  float avg = s / (float)len;
  size_t lr = (size_t)b * NNN + (len - 1);
  float last = xb[lr * DDD + d] * invn[lr];
  float pooled = 0.5f * (last + avg);
  float ssq = block_reduce_sum(pooled * pooled, sm);
  out[(size_t)b * DDD + d] = pooled / fmaxf(sqrtf(ssq), 1e-12f);
}

// ---------------- launch ----------------------------------------------------
extern "C" void kernel_launch(void* const* d_in, const int* in_sizes, int n_in,
                              void* d_out, int out_size, void* d_ws, size_t ws_size,
                              hipStream_t stream) {
  const float* x      = (const float*)d_in[0];
  const int*   ts     = (const int*)d_in[1];
  const float* mask   = (const float*)d_in[2];
  const float* ln1_g  = (const float*)d_in[3];
  const float* ln1_b  = (const float*)d_in[4];
  const float* w_uvqk = (const float*)d_in[5];
  const float* b_uvqk = (const float*)d_in[6];
  const float* ln2_g  = (const float*)d_in[7];
  const float* ln2_b  = (const float*)d_in[8];
  const float* w_o    = (const float*)d_in[9];
  const float* b_o    = (const float*)d_in[10];
  const float* pos_w  = (const float*)d_in[11];
  const float* ts_w   = (const float*)d_in[12];
  float* out = (float*)d_out;

  float* ws = (float*)d_ws;
  const size_t SZ = (size_t)BB * NNN * DDD;           // 8M floats
  float* xb   = ws;                                    // 8M f
  float* buf1 = ws + SZ;                               // 8M f (o)
  float* uvqk = ws + 2 * SZ;                           // 32M f
  __hip_bfloat16* hbf = (__hip_bfloat16*)(ws + 2 * SZ + (size_t)BB * NNN * CCC); // 8M bf16
  __hip_bfloat16* wuT = hbf + SZ;                      // 2 x 4096x1024 bf16
  __hip_bfloat16* woT = wuT + 2 * (size_t)DDD * CCC;   // 2 x 1024x1024 bf16
  float* invn = (float*)(woT + 2 * (size_t)DDD * DDD);
  float* partial = invn + (size_t)BB * NNN;

  // x = x * mask
  mask_x_k<<<(BB * NNN * DDD / 4) / 256, 256, 0, stream>>>(x, mask, xb);

  // transpose+convert weights (both layers)
  for (int l = 0; l < 2; ++l) {
    wconv_k<<<dim3(DDD / 32, CCC / 32), 256, 0, stream>>>(
        w_uvqk + (size_t)l * DDD * CCC, wuT + (size_t)l * CCC * DDD, DDD, CCC);
    wconv_k<<<dim3(DDD / 32, DDD / 32), 256, 0, stream>>>(
        w_o + (size_t)l * DDD * DDD, woT + (size_t)l * DDD * DDD, DDD, DDD);
  }

  for (int l = 0; l < 2; ++l) {
    // h = LN1(x)  (bf16)
    ln_k<<<BB * NNN, 256, 0, stream>>>(xb, ln1_g + l * DDD, ln1_b + l * DDD,
                                       nullptr, 0, hbf);
    // uvqk = silu(h @ w_uvqk + b_uvqk)   (fp32 out)
    gemm_bf_k<0><<<dim3(CCC / 128, BB * NNN / 128), 256, 0, stream>>>(
        (const ushort*)hbf, (const ushort*)(wuT + (size_t)l * CCC * DDD),
        b_uvqk + (size_t)l * CCC, uvqk, DDD, CCC);
    // o = attention -> buf1
    attn_k<<<dim3(NNN / 64, HHH, BB), 256, 0, stream>>>(uvqk, ts, mask, pos_w,
                                                        ts_w, buf1);
    // a = LN2(o) * u  (bf16, reuse hbf)
    ln_k<<<BB * NNN, 256, 0, stream>>>(buf1, ln2_g + l * DDD, ln2_b + l * DDD,
                                       uvqk, CCC, hbf);
    // x += a @ w_o + b_o
    gemm_bf_k<1><<<dim3(DDD / 128, BB * NNN / 128), 256, 0, stream>>>(
        (const ushort*)hbf, (const ushort*)(woT + (size_t)l * DDD * DDD),
        b_o + (size_t)l * DDD, xb, DDD, DDD);
  }

  // pooling
  row_stats_k<<<BB * NNN, 256, 0, stream>>>(xb, invn);
  pool_partial_k<<<dim3(BB, 16), 1024, 0, stream>>>(xb, mask, invn, partial);
  pool_final_k<<<BB, 1024, 0, stream>>>(xb, mask, invn, partial, out);
}

// Round 3
// 813.464 us; speedup vs baseline: 4.0030x; 2.2472x over previous
//
#include <hip/hip_runtime.h>
#include <hip/hip_bf16.h>
#include <cstdint>
#include <cstddef>

// ---------------------------------------------------------------------------
// Round 3: MFMA flash attention (bf16), split uvqk epilogue, precomputed rab.
// ---------------------------------------------------------------------------

#define BB   8
#define NNN  1024
#define DDD  1024
#define HHH  8
#define DVV  128
#define CCC  4096
#define TBK  128

typedef __bf16 bf8_t  __attribute__((ext_vector_type(8)));
typedef float  f4_t   __attribute__((ext_vector_type(4)));

__device__ __forceinline__ float bf2f(ushort u) {
  union { uint i; float f; } v; v.i = ((uint)u) << 16; return v.f;
}
__device__ __forceinline__ ushort f2bf(float f) {
  __hip_bfloat16 h = __float2bfloat16(f);
  return *(ushort*)&h;
}

// ---------------- block reduce ---------------------------------------------
__device__ __forceinline__ float block_reduce_sum(float v, float* sm) {
#pragma unroll
  for (int o = 32; o > 0; o >>= 1) v += __shfl_down(v, o, 64);
  int lane = threadIdx.x & 63;
  int wid  = threadIdx.x >> 6;
  __syncthreads();
  if (lane == 0) sm[wid] = v;
  __syncthreads();
  int nw = blockDim.x >> 6;
  float r = (threadIdx.x < nw) ? sm[threadIdx.x] : 0.f;
#pragma unroll
  for (int o = 8; o > 0; o >>= 1) r += __shfl_down(r, o, 64);
  if (threadIdx.x == 0) sm[0] = r;
  __syncthreads();
  return sm[0];
}

// ---------------- x = x * mask ---------------------------------------------
__global__ __launch_bounds__(256) void mask_x_k(const float* __restrict__ x,
                                                const float* __restrict__ mask,
                                                float* __restrict__ xb) {
  size_t i4 = (size_t)blockIdx.x * 256 + threadIdx.x;
  size_t row = i4 >> 8;
  float m = mask[row];
  float4 v = ((const float4*)x)[i4];
  v.x *= m; v.y *= m; v.z *= m; v.w *= m;
  ((float4*)xb)[i4] = v;
}

// ---------------- weight transpose + bf16 convert ---------------------------
__global__ __launch_bounds__(256) void wconv_k(const float* __restrict__ W,
                                               ushort* __restrict__ Wt,
                                               int K, int Nn) {
  __shared__ float t[32][33];
  int k0 = blockIdx.x * 32, n0 = blockIdx.y * 32;
  int tx = threadIdx.x & 31, ty = threadIdx.x >> 5;
  for (int r = ty; r < 32; r += 8)
    t[r][tx] = W[(size_t)(k0 + r) * Nn + n0 + tx];
  __syncthreads();
  for (int r = ty; r < 32; r += 8)
    Wt[(size_t)(n0 + r) * K + k0 + tx] = f2bf(t[tx][r]);
}

// ---------------- rab precompute: rab[b][i][j] = pos_w[...] + ts_w[bucket] --
__global__ __launch_bounds__(256) void rab_k(const int* __restrict__ ts,
                                             const float* __restrict__ pos_w,
                                             const float* __restrict__ ts_w,
                                             ushort* __restrict__ rabb) {
  int jt = blockIdx.x, it = blockIdx.y, b = blockIdx.z;
  if (jt > it) return;
  int j = jt * 128 + (threadIdx.x & 127);
  int half = threadIdx.x >> 7;
  int tsj = ts[(size_t)b * NNN + j];
  for (int rr = 0; rr < 64; ++rr) {
    int i = it * 128 + rr * 2 + half;
    int ii = i + 1; if (ii > NNN - 1) ii = NNN - 1;
    int tsi = ts[(size_t)b * NNN + ii];
    float af = fabsf((float)(tsi - tsj));
    af = fmaxf(af, 1.f);
    int bkt = (int)__log2f(af);
    bkt = min(max(bkt, 0), TBK);
    float rab = pos_w[i - j + NNN - 1] + ts_w[bkt];
    rabb[((size_t)b * NNN + i) * NNN + j] = f2bf(rab);
  }
}

// ---------------- LayerNorm (optionally * u), bf16 output -------------------
__global__ __launch_bounds__(256) void ln_k(const float* __restrict__ X,
                                            const float* __restrict__ g,
                                            const float* __restrict__ bsh,
                                            const float* __restrict__ umat,
                                            int ustride,
                                            ushort* __restrict__ Y) {
  __shared__ float sm[16];
  size_t row = blockIdx.x;
  const float* xr = X + row * DDD;
  int d = threadIdx.x * 4;
  float4 xv = *(const float4*)(xr + d);
  float s = xv.x + xv.y + xv.z + xv.w;
  s = block_reduce_sum(s, sm);
  float mu = s * (1.f / 1024.f);
  float d0 = xv.x - mu, d1 = xv.y - mu, d2 = xv.z - mu, d3 = xv.w - mu;
  float ss = d0 * d0 + d1 * d1 + d2 * d2 + d3 * d3;
  ss = block_reduce_sum(ss, sm);
  float rs = rsqrtf(ss * (1.f / 1024.f) + 1e-6f);
  float y0 = d0 * rs * g[d + 0] + bsh[d + 0];
  float y1 = d1 * rs * g[d + 1] + bsh[d + 1];
  float y2 = d2 * rs * g[d + 2] + bsh[d + 2];
  float y3 = d3 * rs * g[d + 3] + bsh[d + 3];
  if (umat != nullptr) {
    const float* ur = umat + row * (size_t)ustride + d;
    y0 *= ur[0]; y1 *= ur[1]; y2 *= ur[2]; y3 *= ur[3];
  }
  ushort tmp[4] = { f2bf(y0), f2bf(y1), f2bf(y2), f2bf(y3) };
  *(uint2*)(Y + row * DDD + d) = *(uint2*)tmp;
}

// ---------------- bf16 MFMA GEMM -------------------------------------------
// MODE 1: C[row*Nn+col] += z (+bias)            (w_o GEMM, Nn=1024)
// MODE 2: uvqk split: col<1024 -> C (u, fp32, stride 1024)
//                     col>=1024 -> Cb (qkv bf16, stride 3072, col-1024)
template <int MODE>
__global__ __launch_bounds__(256) void gemm_bf_k(const ushort* __restrict__ A,
                                                 const ushort* __restrict__ Bt,
                                                 const float* __restrict__ bias,
                                                 float* __restrict__ C,
                                                 ushort* __restrict__ Cb,
                                                 int K, int Nn) {
  __shared__ alignas(16) ushort As[128 * 32];
  __shared__ alignas(16) ushort Bs[128 * 32];
  int tid = threadIdx.x;
  int wave = tid >> 6, lane = tid & 63;
  int quad = lane >> 4, l16 = lane & 15;
  int wm = wave >> 1, wn = wave & 1;
  int m0 = blockIdx.y * 128, n0 = blockIdx.x * 128;

  f4_t acc[4][4] = {};

  int r_l = tid >> 2;
  int p   = tid & 3;

  for (int k0 = 0; k0 < K; k0 += 32) {
    __syncthreads();
#pragma unroll
    for (int g = 0; g < 2; ++g) {
      int row = g * 64 + r_l;
      int q = (p - (row >> 1)) & 3;
      __builtin_amdgcn_global_load_lds(
          (const __attribute__((address_space(1))) void*)(A + (size_t)(m0 + row) * K + k0 + q * 8),
          (__attribute__((address_space(3))) void*)(As + (g * 64 + wave * 16) * 32),
          16, 0, 0);
      __builtin_amdgcn_global_load_lds(
          (const __attribute__((address_space(1))) void*)(Bt + (size_t)(n0 + row) * K + k0 + q * 8),
          (__attribute__((address_space(3))) void*)(Bs + (g * 64 + wave * 16) * 32),
          16, 0, 0);
    }
    __syncthreads();

    bf8_t af[4], bfr[4];
#pragma unroll
    for (int t = 0; t < 4; ++t) {
      int row = wm * 64 + t * 16 + l16;
      af[t] = *(const bf8_t*)&As[row * 32 + ((quad + (row >> 1)) & 3) * 8];
      int col = wn * 64 + t * 16 + l16;
      bfr[t] = *(const bf8_t*)&Bs[col * 32 + ((quad + (col >> 1)) & 3) * 8];
    }
#pragma unroll
    for (int i = 0; i < 4; ++i)
#pragma unroll
      for (int j = 0; j < 4; ++j)
        acc[i][j] = __builtin_amdgcn_mfma_f32_16x16x32_bf16(af[i], bfr[j],
                                                            acc[i][j], 0, 0, 0);
  }

#pragma unroll
  for (int j = 0; j < 4; ++j) {
    int col = n0 + wn * 64 + j * 16 + l16;
    float bz = bias[col];
#pragma unroll
    for (int i = 0; i < 4; ++i) {
      int rbase = m0 + wm * 64 + i * 16 + quad * 4;
#pragma unroll
      for (int r = 0; r < 4; ++r) {
        float z = acc[i][j][r] + bz;
        int row = rbase + r;
        if (MODE == 1) {
          C[(size_t)row * Nn + col] += z;
        } else {
          float s = z / (1.f + __expf(-z));
          if (col < 1024) C[(size_t)row * 1024 + col] = s;
          else Cb[(size_t)row * 3072 + (col - 1024)] = f2bf(s);
        }
      }
    }
  }
}

// ---------------- V transpose: qkv v-part [n][h*128+dv] -> vt[b,h,dv,n] -----
__global__ __launch_bounds__(256) void vt_k(const ushort* __restrict__ qkv,
                                            ushort* __restrict__ vt) {
  __shared__ ushort t[32][33];
  int bh = blockIdx.z; int b = bh >> 3, h = bh & 7;
  int nt = blockIdx.x * 32, dt = blockIdx.y * 32;
  int tx = threadIdx.x & 31, ty = threadIdx.x >> 5;
  for (int rr = ty; rr < 32; rr += 8)
    t[rr][tx] = qkv[(size_t)(b * NNN + nt + rr) * 3072 + h * 128 + dt + tx];
  __syncthreads();
  for (int rr = ty; rr < 32; rr += 8)
    vt[((size_t)bh * 128 + dt + rr) * NNN + nt + tx] = t[tx][rr];
}

// ---------------- MFMA flash attention --------------------------------------
// grid (8 qtiles, H, B), 256 thr = 4 waves. Per block: 128 q-rows.
// LDS: Ks 64x128 bf16 (16-chunk swizzle), Vs=V^T 128x64 (8-chunk swizzle),
//      Ps 128x64 (8-chunk swizzle). Q frags in regs (staged via Ks).
__global__ __launch_bounds__(256, 2) void attn_mfma_k(
    const ushort* __restrict__ qkv, const ushort* __restrict__ vt,
    const ushort* __restrict__ rabb, const float* __restrict__ mask,
    float* __restrict__ o) {
  __shared__ alignas(16) ushort Ks[64 * 128];
  __shared__ alignas(16) ushort Vs[128 * 64];
  __shared__ alignas(16) ushort Ps[128 * 64];
  int h = blockIdx.y, b = blockIdx.z;
  int n0 = (((int)blockIdx.x + b) & 7) * 128;   // work-balance swizzle
  int tid = threadIdx.x, w = tid >> 6, lane = tid & 63;
  int quad = lane >> 4, l16 = lane & 15;

  // ---- Q fragments into registers, staged through Ks ----
  bf8_t qf[2][4];
  const ushort* qg0 = qkv + ((size_t)(b * NNN + n0)) * 3072 + 1024 + h * 128;
#pragma unroll
  for (int g = 0; g < 2; ++g) {
    __syncthreads();
#pragma unroll
    for (int t = 0; t < 4; ++t) {
      int lrow = w * 16 + t * 4 + (lane >> 4);
      int q = ((lane & 15) - lrow) & 15;
      __builtin_amdgcn_global_load_lds(
          (const __attribute__((address_space(1))) void*)(qg0 + (size_t)(g * 64 + lrow) * 3072 + q * 8),
          (__attribute__((address_space(3))) void*)(Ks + (w * 16 + t * 4) * 128),
          16, 0, 0);
    }
    __syncthreads();
    if ((w >> 1) == g) {
#pragma unroll
      for (int ti = 0; ti < 2; ++ti)
#pragma unroll
        for (int kk = 0; kk < 4; ++kk) {
          int lr = (w & 1) * 32 + ti * 16 + l16;
          qf[ti][kk] = *(const bf8_t*)&Ks[lr * 128 + (((kk * 4 + quad) + lr) & 15) * 8];
        }
    }
  }

  f4_t oacc[2][8] = {};
  const ushort* kg0 = qkv + (size_t)b * NNN * 3072 + 2048 + h * 128;
  const ushort* vg0 = vt + (size_t)(b * 8 + h) * 128 * NNN;
  int mtmax = n0 / 64 + 2;

  for (int mt = 0; mt < mtmax; ++mt) {
    int m0 = mt * 64;
    __syncthreads();   // prior consumers of Ks/Vs/Ps done
    // stage K tile (64 rows x 128 k)
#pragma unroll
    for (int t = 0; t < 4; ++t) {
      int lrow = w * 16 + t * 4 + (lane >> 4);
      int q = ((lane & 15) - lrow) & 15;
      __builtin_amdgcn_global_load_lds(
          (const __attribute__((address_space(1))) void*)(kg0 + (size_t)(m0 + lrow) * 3072 + q * 8),
          (__attribute__((address_space(3))) void*)(Ks + (w * 16 + t * 4) * 128),
          16, 0, 0);
    }
    // stage V^T tile (128 dv x 64 m)
#pragma unroll
    for (int t = 0; t < 4; ++t) {
      int dv = w * 32 + t * 8 + (lane >> 3);
      int q = ((lane & 7) - dv) & 7;
      __builtin_amdgcn_global_load_lds(
          (const __attribute__((address_space(1))) void*)(vg0 + (size_t)dv * NNN + m0 + q * 8),
          (__attribute__((address_space(3))) void*)(Vs + (w * 32 + t * 8) * 64),
          16, 0, 0);
    }
    __syncthreads();

    // ---- S = Q K^T (per wave: 32q x 64m) ----
    f4_t sacc[2][4] = {};
#pragma unroll
    for (int kk = 0; kk < 4; ++kk) {
      bf8_t kf[4];
#pragma unroll
      for (int tj = 0; tj < 4; ++tj) {
        int lr = tj * 16 + l16;
        kf[tj] = *(const bf8_t*)&Ks[lr * 128 + (((kk * 4 + quad) + lr) & 15) * 8];
      }
#pragma unroll
      for (int ti = 0; ti < 2; ++ti)
#pragma unroll
        for (int tj = 0; tj < 4; ++tj)
          sacc[ti][tj] = __builtin_amdgcn_mfma_f32_16x16x32_bf16(
              qf[ti][kk], kf[tj], sacc[ti][tj], 0, 0, 0);
    }

    // ---- P = silu(S + rab)/N * causal * mask -> Ps (bf16, A-layout rows) ----
#pragma unroll
    for (int tj = 0; tj < 4; ++tj) {
      int m = tj * 16 + l16;
      int gj = m0 + m;
      float msc = mask[(size_t)b * NNN + gj] * (1.f / 1024.f);
#pragma unroll
      for (int ti = 0; ti < 2; ++ti) {
        int qb = w * 32 + ti * 16 + quad * 4;
#pragma unroll
        for (int r = 0; r < 4; ++r) {
          int q = qb + r;
          int gi = n0 + q;
          float rab = bf2f(rabb[((size_t)b * NNN + gi) * NNN + gj]);
          float z = sacc[ti][tj][r] + rab;
          float pp = z / (1.f + __expf(-z)) * msc;
          if (gj > gi) pp = 0.f;
          Ps[q * 64 + (((m >> 3) + q) & 7) * 8 + (m & 7)] = f2bf(pp);
        }
      }
    }

    // ---- O += P V (reads own wave's Ps rows; same-wave dep via lgkmcnt) ----
#pragma unroll
    for (int kk = 0; kk < 2; ++kk) {
      bf8_t pf[2], vf[8];
#pragma unroll
      for (int ti = 0; ti < 2; ++ti) {
        int q = w * 32 + ti * 16 + l16;
        pf[ti] = *(const bf8_t*)&Ps[q * 64 + (((kk * 4 + quad) + q) & 7) * 8];
      }
#pragma unroll
      for (int tj = 0; tj < 8; ++tj) {
        int dv = tj * 16 + l16;
        vf[tj] = *(const bf8_t*)&Vs[dv * 64 + (((kk * 4 + quad) + dv) & 7) * 8];
      }
#pragma unroll
      for (int ti = 0; ti < 2; ++ti)
#pragma unroll
        for (int tj = 0; tj < 8; ++tj)
          oacc[ti][tj] = __builtin_amdgcn_mfma_f32_16x16x32_bf16(
              pf[ti], vf[tj], oacc[ti][tj], 0, 0, 0);
    }
  }

  // ---- store O ----
#pragma unroll
  for (int ti = 0; ti < 2; ++ti)
#pragma unroll
    for (int tj = 0; tj < 8; ++tj) {
      int col = h * 128 + tj * 16 + l16;
#pragma unroll
      for (int r = 0; r < 4; ++r) {
        int gi = n0 + w * 32 + ti * 16 + quad * 4 + r;
        o[((size_t)(b * NNN + gi)) * DDD + col] = oacc[ti][tj][r];
      }
    }
}

// ---------------- pooling ---------------------------------------------------
__global__ __launch_bounds__(256) void row_stats_k(const float* __restrict__ xb,
                                                   float* __restrict__ invn) {
  __shared__ float sm[16];
  size_t row = blockIdx.x;
  int d = threadIdx.x * 4;
  float4 xv = *(const float4*)(xb + row * DDD + d);
  float ss = xv.x * xv.x + xv.y * xv.y + xv.z * xv.z + xv.w * xv.w;
  ss = block_reduce_sum(ss, sm);
  if (threadIdx.x == 0) invn[row] = 1.f / fmaxf(sqrtf(ss), 1e-12f);
}

__global__ __launch_bounds__(1024) void pool_partial_k(const float* __restrict__ xb,
                                                       const float* __restrict__ mask,
                                                       const float* __restrict__ invn,
                                                       float* __restrict__ partial) {
  int b = blockIdx.x, c = blockIdx.y, d = threadIdx.x;
  float s = 0.f;
  int nbeg = c * 64;
  for (int n = nbeg; n < nbeg + 64; ++n) {
    size_t r = (size_t)b * NNN + n;
    s += xb[r * DDD + d] * mask[r] * invn[r];
  }
  partial[((size_t)b * 16 + c) * DDD + d] = s;
}

__global__ __launch_bounds__(1024) void pool_final_k(const float* __restrict__ xb,
                                                     const float* __restrict__ mask,
                                                     const float* __restrict__ invn,
                                                     const float* __restrict__ partial,
                                                     float* __restrict__ out) {
  __shared__ float sm[16];
  int b = blockIdx.x, d = threadIdx.x;
  float msum = mask[(size_t)b * NNN + d];
  msum = block_reduce_sum(msum, sm);
  int len = (int)(msum + 0.5f);
  float s = 0.f;
#pragma unroll
  for (int c = 0; c < 16; ++c) s += partial[((size_t)b * 16 + c) * DDD + d];
  float avg = s / (float)len;
  size_t lr = (size_t)b * NNN + (len - 1);
  float last = xb[lr * DDD + d] * invn[lr];
  float pooled = 0.5f * (last + avg);
  float ssq = block_reduce_sum(pooled * pooled, sm);
  out[(size_t)b * DDD + d] = pooled / fmaxf(sqrtf(ssq), 1e-12f);
}

// ---------------- launch ----------------------------------------------------
extern "C" void kernel_launch(void* const* d_in, const int* in_sizes, int n_in,
                              void* d_out, int out_size, void* d_ws, size_t ws_size,
                              hipStream_t stream) {
  const float* x      = (const float*)d_in[0];
  const int*   ts     = (const int*)d_in[1];
  const float* mask   = (const float*)d_in[2];
  const float* ln1_g  = (const float*)d_in[3];
  const float* ln1_b  = (const float*)d_in[4];
  const float* w_uvqk = (const float*)d_in[5];
  const float* b_uvqk = (const float*)d_in[6];
  const float* ln2_g  = (const float*)d_in[7];
  const float* ln2_b  = (const float*)d_in[8];
  const float* w_o    = (const float*)d_in[9];
  const float* b_o    = (const float*)d_in[10];
  const float* pos_w  = (const float*)d_in[11];
  const float* ts_w   = (const float*)d_in[12];
  float* out = (float*)d_out;

  float* ws = (float*)d_ws;
  const size_t SZ = (size_t)BB * NNN * DDD;            // 8M
  float* xb   = ws;                                     // 8M f
  float* buf1 = ws + SZ;                                // 8M f (o)
  float* ubuf = ws + 2 * SZ;                            // 8M f (u)
  ushort* hbf = (ushort*)(ws + 3 * SZ);                 // 8M bf16
  ushort* wuT = hbf + SZ;                               // 8M bf16
  ushort* woT = wuT + 2 * (size_t)DDD * CCC;            // 2M bf16
  ushort* qkvb = woT + 2 * (size_t)DDD * DDD;           // 8192*3072 bf16
  ushort* vtb  = qkvb + (size_t)BB * NNN * 3072;        // 64*128*1024 bf16
  ushort* rabb = vtb + (size_t)BB * HHH * DVV * NNN;    // 8*1024*1024 bf16
  float* invn = (float*)(rabb + (size_t)BB * NNN * NNN);
  float* partial = invn + (size_t)BB * NNN;

  mask_x_k<<<(BB * NNN * DDD / 4) / 256, 256, 0, stream>>>(x, mask, xb);

  for (int l = 0; l < 2; ++l) {
    wconv_k<<<dim3(DDD / 32, CCC / 32), 256, 0, stream>>>(
        w_uvqk + (size_t)l * DDD * CCC, wuT + (size_t)l * CCC * DDD, DDD, CCC);
    wconv_k<<<dim3(DDD / 32, DDD / 32), 256, 0, stream>>>(
        w_o + (size_t)l * DDD * DDD, woT + (size_t)l * DDD * DDD, DDD, DDD);
  }

  rab_k<<<dim3(8, 8, BB), 256, 0, stream>>>(ts, pos_w, ts_w, rabb);

  for (int l = 0; l < 2; ++l) {
    ln_k<<<BB * NNN, 256, 0, stream>>>(xb, ln1_g + l * DDD, ln1_b + l * DDD,
                                       nullptr, 0, hbf);
    gemm_bf_k<2><<<dim3(CCC / 128, BB * NNN / 128), 256, 0, stream>>>(
        hbf, wuT + (size_t)l * CCC * DDD, b_uvqk + (size_t)l * CCC,
        ubuf, qkvb, DDD, CCC);
    vt_k<<<dim3(NNN / 32, DVV / 32, BB * HHH), 256, 0, stream>>>(qkvb, vtb);
    attn_mfma_k<<<dim3(NNN / 128, HHH, BB), 256, 0, stream>>>(
        qkvb, vtb, rabb, mask, buf1);
    ln_k<<<BB * NNN, 256, 0, stream>>>(buf1, ln2_g + l * DDD, ln2_b + l * DDD,
                                       ubuf, DDD, hbf);
    gemm_bf_k<1><<<dim3(DDD / 128, BB * NNN / 128), 256, 0, stream>>>(
        hbf, woT + (size_t)l * DDD * DDD, b_o + (size_t)l * DDD,
        xb, nullptr, DDD, DDD);
  }

  row_stats_k<<<BB * NNN, 256, 0, stream>>>(xb, invn);
  pool_partial_k<<<dim3(BB, 16), 1024, 0, stream>>>(xb, mask, invn, partial);
  pool_final_k<<<BB, 1024, 0, stream>>>(xb, mask, invn, partial, out);
}

// Round 4
// 734.330 us; speedup vs baseline: 4.4344x; 1.1078x over previous
//
#include <hip/hip_runtime.h>
#include <hip/hip_bf16.h>
#include <cstdint>
#include <cstddef>

// ---------------------------------------------------------------------------
// Round 4: attention restructured for occupancy/latency:
//  - 64-q blocks (grid 1024), LDS 40 KB -> 4 blocks/CU (16 waves/CU).
//  - rab prefetched into registers alongside K/V staging (off critical path).
//  - qtile swizzle (bx+by+2bz)&15 to balance causal work across CUs.
// GEMMs / LN / pooling unchanged from round 3.
// ---------------------------------------------------------------------------

#define BB   8
#define NNN  1024
#define DDD  1024
#define HHH  8
#define DVV  128
#define CCC  4096
#define TBK  128

typedef __bf16 bf8_t  __attribute__((ext_vector_type(8)));
typedef float  f4_t   __attribute__((ext_vector_type(4)));

__device__ __forceinline__ float bf2f(ushort u) {
  union { uint i; float f; } v; v.i = ((uint)u) << 16; return v.f;
}
__device__ __forceinline__ ushort f2bf(float f) {
  __hip_bfloat16 h = __float2bfloat16(f);
  return *(ushort*)&h;
}

// ---------------- block reduce ---------------------------------------------
__device__ __forceinline__ float block_reduce_sum(float v, float* sm) {
#pragma unroll
  for (int o = 32; o > 0; o >>= 1) v += __shfl_down(v, o, 64);
  int lane = threadIdx.x & 63;
  int wid  = threadIdx.x >> 6;
  __syncthreads();
  if (lane == 0) sm[wid] = v;
  __syncthreads();
  int nw = blockDim.x >> 6;
  float r = (threadIdx.x < nw) ? sm[threadIdx.x] : 0.f;
#pragma unroll
  for (int o = 8; o > 0; o >>= 1) r += __shfl_down(r, o, 64);
  if (threadIdx.x == 0) sm[0] = r;
  __syncthreads();
  return sm[0];
}

// ---------------- x = x * mask ---------------------------------------------
__global__ __launch_bounds__(256) void mask_x_k(const float* __restrict__ x,
                                                const float* __restrict__ mask,
                                                float* __restrict__ xb) {
  size_t i4 = (size_t)blockIdx.x * 256 + threadIdx.x;
  size_t row = i4 >> 8;
  float m = mask[row];
  float4 v = ((const float4*)x)[i4];
  v.x *= m; v.y *= m; v.z *= m; v.w *= m;
  ((float4*)xb)[i4] = v;
}

// ---------------- weight transpose + bf16 convert ---------------------------
__global__ __launch_bounds__(256) void wconv_k(const float* __restrict__ W,
                                               ushort* __restrict__ Wt,
                                               int K, int Nn) {
  __shared__ float t[32][33];
  int k0 = blockIdx.x * 32, n0 = blockIdx.y * 32;
  int tx = threadIdx.x & 31, ty = threadIdx.x >> 5;
  for (int r = ty; r < 32; r += 8)
    t[r][tx] = W[(size_t)(k0 + r) * Nn + n0 + tx];
  __syncthreads();
  for (int r = ty; r < 32; r += 8)
    Wt[(size_t)(n0 + r) * K + k0 + tx] = f2bf(t[tx][r]);
}

// ---------------- rab precompute: rab[b][i][j] = pos_w[...] + ts_w[bucket] --
__global__ __launch_bounds__(256) void rab_k(const int* __restrict__ ts,
                                             const float* __restrict__ pos_w,
                                             const float* __restrict__ ts_w,
                                             ushort* __restrict__ rabb) {
  int jt = blockIdx.x, it = blockIdx.y, b = blockIdx.z;
  if (jt > it) return;
  int j = jt * 128 + (threadIdx.x & 127);
  int half = threadIdx.x >> 7;
  int tsj = ts[(size_t)b * NNN + j];
  for (int rr = 0; rr < 64; ++rr) {
    int i = it * 128 + rr * 2 + half;
    int ii = i + 1; if (ii > NNN - 1) ii = NNN - 1;
    int tsi = ts[(size_t)b * NNN + ii];
    float af = fabsf((float)(tsi - tsj));
    af = fmaxf(af, 1.f);
    int bkt = (int)__log2f(af);
    bkt = min(max(bkt, 0), TBK);
    float rab = pos_w[i - j + NNN - 1] + ts_w[bkt];
    rabb[((size_t)b * NNN + i) * NNN + j] = f2bf(rab);
  }
}

// ---------------- LayerNorm (optionally * u), bf16 output -------------------
__global__ __launch_bounds__(256) void ln_k(const float* __restrict__ X,
                                            const float* __restrict__ g,
                                            const float* __restrict__ bsh,
                                            const float* __restrict__ umat,
                                            int ustride,
                                            ushort* __restrict__ Y) {
  __shared__ float sm[16];
  size_t row = blockIdx.x;
  const float* xr = X + row * DDD;
  int d = threadIdx.x * 4;
  float4 xv = *(const float4*)(xr + d);
  float s = xv.x + xv.y + xv.z + xv.w;
  s = block_reduce_sum(s, sm);
  float mu = s * (1.f / 1024.f);
  float d0 = xv.x - mu, d1 = xv.y - mu, d2 = xv.z - mu, d3 = xv.w - mu;
  float ss = d0 * d0 + d1 * d1 + d2 * d2 + d3 * d3;
  ss = block_reduce_sum(ss, sm);
  float rs = rsqrtf(ss * (1.f / 1024.f) + 1e-6f);
  float y0 = d0 * rs * g[d + 0] + bsh[d + 0];
  float y1 = d1 * rs * g[d + 1] + bsh[d + 1];
  float y2 = d2 * rs * g[d + 2] + bsh[d + 2];
  float y3 = d3 * rs * g[d + 3] + bsh[d + 3];
  if (umat != nullptr) {
    const float* ur = umat + row * (size_t)ustride + d;
    y0 *= ur[0]; y1 *= ur[1]; y2 *= ur[2]; y3 *= ur[3];
  }
  ushort tmp[4] = { f2bf(y0), f2bf(y1), f2bf(y2), f2bf(y3) };
  *(uint2*)(Y + row * DDD + d) = *(uint2*)tmp;
}

// ---------------- bf16 MFMA GEMM -------------------------------------------
// MODE 1: C[row*Nn+col] += z (+bias)            (w_o GEMM, Nn=1024)
// MODE 2: uvqk split: col<1024 -> C (u, fp32, stride 1024)
//                     col>=1024 -> Cb (qkv bf16, stride 3072, col-1024)
template <int MODE>
__global__ __launch_bounds__(256) void gemm_bf_k(const ushort* __restrict__ A,
                                                 const ushort* __restrict__ Bt,
                                                 const float* __restrict__ bias,
                                                 float* __restrict__ C,
                                                 ushort* __restrict__ Cb,
                                                 int K, int Nn) {
  __shared__ alignas(16) ushort As[128 * 32];
  __shared__ alignas(16) ushort Bs[128 * 32];
  int tid = threadIdx.x;
  int wave = tid >> 6, lane = tid & 63;
  int quad = lane >> 4, l16 = lane & 15;
  int wm = wave >> 1, wn = wave & 1;
  int m0 = blockIdx.y * 128, n0 = blockIdx.x * 128;

  f4_t acc[4][4] = {};

  int r_l = tid >> 2;
  int p   = tid & 3;

  for (int k0 = 0; k0 < K; k0 += 32) {
    __syncthreads();
#pragma unroll
    for (int g = 0; g < 2; ++g) {
      int row = g * 64 + r_l;
      int q = (p - (row >> 1)) & 3;
      __builtin_amdgcn_global_load_lds(
          (const __attribute__((address_space(1))) void*)(A + (size_t)(m0 + row) * K + k0 + q * 8),
          (__attribute__((address_space(3))) void*)(As + (g * 64 + wave * 16) * 32),
          16, 0, 0);
      __builtin_amdgcn_global_load_lds(
          (const __attribute__((address_space(1))) void*)(Bt + (size_t)(n0 + row) * K + k0 + q * 8),
          (__attribute__((address_space(3))) void*)(Bs + (g * 64 + wave * 16) * 32),
          16, 0, 0);
    }
    __syncthreads();

    bf8_t af[4], bfr[4];
#pragma unroll
    for (int t = 0; t < 4; ++t) {
      int row = wm * 64 + t * 16 + l16;
      af[t] = *(const bf8_t*)&As[row * 32 + ((quad + (row >> 1)) & 3) * 8];
      int col = wn * 64 + t * 16 + l16;
      bfr[t] = *(const bf8_t*)&Bs[col * 32 + ((quad + (col >> 1)) & 3) * 8];
    }
#pragma unroll
    for (int i = 0; i < 4; ++i)
#pragma unroll
      for (int j = 0; j < 4; ++j)
        acc[i][j] = __builtin_amdgcn_mfma_f32_16x16x32_bf16(af[i], bfr[j],
                                                            acc[i][j], 0, 0, 0);
  }

#pragma unroll
  for (int j = 0; j < 4; ++j) {
    int col = n0 + wn * 64 + j * 16 + l16;
    float bz = bias[col];
#pragma unroll
    for (int i = 0; i < 4; ++i) {
      int rbase = m0 + wm * 64 + i * 16 + quad * 4;
#pragma unroll
      for (int r = 0; r < 4; ++r) {
        float z = acc[i][j][r] + bz;
        int row = rbase + r;
        if (MODE == 1) {
          C[(size_t)row * Nn + col] += z;
        } else {
          float s = z / (1.f + __expf(-z));
          if (col < 1024) C[(size_t)row * 1024 + col] = s;
          else Cb[(size_t)row * 3072 + (col - 1024)] = f2bf(s);
        }
      }
    }
  }
}

// ---------------- V transpose: qkv v-part [n][h*128+dv] -> vt[b,h,dv,n] -----
__global__ __launch_bounds__(256) void vt_k(const ushort* __restrict__ qkv,
                                            ushort* __restrict__ vt) {
  __shared__ ushort t[32][33];
  int bh = blockIdx.z; int b = bh >> 3, h = bh & 7;
  int nt = blockIdx.x * 32, dt = blockIdx.y * 32;
  int tx = threadIdx.x & 31, ty = threadIdx.x >> 5;
  for (int rr = ty; rr < 32; rr += 8)
    t[rr][tx] = qkv[(size_t)(b * NNN + nt + rr) * 3072 + h * 128 + dt + tx];
  __syncthreads();
  for (int rr = ty; rr < 32; rr += 8)
    vt[((size_t)bh * 128 + dt + rr) * NNN + nt + tx] = t[tx][rr];
}

// ---------------- MFMA flash attention --------------------------------------
// grid (16 qtiles, H, B), 256 thr = 4 waves. Per block: 64 q-rows.
// Wave w owns q rows w*16..w*16+15. Per m-tile (64 m):
//   stage K(64x128)/V^T(128x64) via global_load_lds + rab into regs, then
//   S = Q K^T (16 MFMA), epilogue, Ps (same-wave LDS round-trip), PV (16 MFMA).
__global__ __launch_bounds__(256, 4) void attn_mfma_k(
    const ushort* __restrict__ qkv, const ushort* __restrict__ vt,
    const ushort* __restrict__ rabb, const float* __restrict__ mask,
    float* __restrict__ o) {
  __shared__ alignas(16) ushort Ks[64 * 128];   // 16 KB
  __shared__ alignas(16) ushort Vs[128 * 64];   // 16 KB
  __shared__ alignas(16) ushort Ps[64 * 64];    // 8 KB
  int h = blockIdx.y, b = blockIdx.z;
  int qt = ((int)blockIdx.x + (int)blockIdx.y + 2 * (int)blockIdx.z) & 15;
  int n0 = qt * 64;
  int tid = threadIdx.x, w = tid >> 6, lane = tid & 63;
  int quad = lane >> 4, l16 = lane & 15;

  // ---- stage Q (64x128) through Ks, move to regs ----
  const ushort* qg0 = qkv + ((size_t)(b * NNN + n0)) * 3072 + 1024 + h * 128;
#pragma unroll
  for (int t = 0; t < 4; ++t) {
    int lrow = w * 16 + t * 4 + (lane >> 4);
    int q = ((lane & 15) - lrow) & 15;
    __builtin_amdgcn_global_load_lds(
        (const __attribute__((address_space(1))) void*)(qg0 + (size_t)lrow * 3072 + q * 8),
        (__attribute__((address_space(3))) void*)(Ks + (w * 16 + t * 4) * 128),
        16, 0, 0);
  }
  __syncthreads();
  bf8_t qf[4];
  {
    int lr = w * 16 + l16;
#pragma unroll
    for (int kk = 0; kk < 4; ++kk)
      qf[kk] = *(const bf8_t*)&Ks[lr * 128 + (((kk * 4 + quad) + lr) & 15) * 8];
  }

  f4_t oacc[8] = {};
  const ushort* kg0 = qkv + (size_t)b * NNN * 3072 + 2048 + h * 128;
  const ushort* vg0 = vt + (size_t)(b * 8 + h) * 128 * NNN;
  const ushort* rb0 = rabb + ((size_t)(b * NNN + n0 + w * 16 + quad * 4)) * NNN;
  const float* mk0 = mask + (size_t)b * NNN;
  int mtmax = qt + 1;

  for (int mt = 0; mt < mtmax; ++mt) {
    int m0 = mt * 64;
    __syncthreads();   // prior consumers of Ks/Vs done (incl. qf reads on it 0)
    // stage K tile (64 rows x 128 k)
#pragma unroll
    for (int t = 0; t < 4; ++t) {
      int lrow = w * 16 + t * 4 + (lane >> 4);
      int q = ((lane & 15) - lrow) & 15;
      __builtin_amdgcn_global_load_lds(
          (const __attribute__((address_space(1))) void*)(kg0 + (size_t)(m0 + lrow) * 3072 + q * 8),
          (__attribute__((address_space(3))) void*)(Ks + (w * 16 + t * 4) * 128),
          16, 0, 0);
    }
    // stage V^T tile (128 dv x 64 m)
#pragma unroll
    for (int t = 0; t < 4; ++t) {
      int dv = w * 32 + t * 8 + (lane >> 3);
      int q = ((lane & 7) - dv) & 7;
      __builtin_amdgcn_global_load_lds(
          (const __attribute__((address_space(1))) void*)(vg0 + (size_t)dv * NNN + m0 + q * 8),
          (__attribute__((address_space(3))) void*)(Vs + (w * 32 + t * 8) * 64),
          16, 0, 0);
    }
    // rab prefetch into registers (drains with the staging barrier below)
    ushort rv[4][4];
#pragma unroll
    for (int tj = 0; tj < 4; ++tj)
#pragma unroll
      for (int r = 0; r < 4; ++r)
        rv[tj][r] = rb0[(size_t)r * NNN + m0 + tj * 16 + l16];
    __syncthreads();

    // ---- S = Q K^T (per wave: 16q x 64m) ----
    f4_t sacc[4] = {};
#pragma unroll
    for (int kk = 0; kk < 4; ++kk) {
      bf8_t kf[4];
#pragma unroll
      for (int tj = 0; tj < 4; ++tj) {
        int lr = tj * 16 + l16;
        kf[tj] = *(const bf8_t*)&Ks[lr * 128 + (((kk * 4 + quad) + lr) & 15) * 8];
      }
#pragma unroll
      for (int tj = 0; tj < 4; ++tj)
        sacc[tj] = __builtin_amdgcn_mfma_f32_16x16x32_bf16(qf[kk], kf[tj],
                                                           sacc[tj], 0, 0, 0);
    }

    // ---- P = silu(S + rab)/N * causal * mask -> Ps (A-layout rows) ----
#pragma unroll
    for (int tj = 0; tj < 4; ++tj) {
      int m = tj * 16 + l16;
      int gj = m0 + m;
      float msc = mk0[gj] * (1.f / 1024.f);
#pragma unroll
      for (int r = 0; r < 4; ++r) {
        int q = w * 16 + quad * 4 + r;
        int gi = n0 + q;
        float z = sacc[tj][r] + bf2f(rv[tj][r]);
        float pp = z / (1.f + __expf(-z)) * msc;
        if (gj > gi) pp = 0.f;
        Ps[q * 64 + (((m >> 3) + q) & 7) * 8 + (m & 7)] = f2bf(pp);
      }
    }

    // ---- O += P V (own wave's Ps rows; same-wave dep via lgkmcnt) ----
#pragma unroll
    for (int kk = 0; kk < 2; ++kk) {
      bf8_t pf, vf[8];
      {
        int q = w * 16 + l16;
        pf = *(const bf8_t*)&Ps[q * 64 + (((kk * 4 + quad) + q) & 7) * 8];
      }
#pragma unroll
      for (int tj = 0; tj < 8; ++tj) {
        int dv = tj * 16 + l16;
        vf[tj] = *(const bf8_t*)&Vs[dv * 64 + (((kk * 4 + quad) + dv) & 7) * 8];
      }
#pragma unroll
      for (int tj = 0; tj < 8; ++tj)
        oacc[tj] = __builtin_amdgcn_mfma_f32_16x16x32_bf16(pf, vf[tj],
                                                           oacc[tj], 0, 0, 0);
    }
  }

  // ---- store O ----
#pragma unroll
  for (int tj = 0; tj < 8; ++tj) {
    int col = h * 128 + tj * 16 + l16;
#pragma unroll
    for (int r = 0; r < 4; ++r) {
      int gi = n0 + w * 16 + quad * 4 + r;
      o[((size_t)(b * NNN + gi)) * DDD + col] = oacc[tj][r];
    }
  }
}

// ---------------- pooling ---------------------------------------------------
__global__ __launch_bounds__(256) void row_stats_k(const float* __restrict__ xb,
                                                   float* __restrict__ invn) {
  __shared__ float sm[16];
  size_t row = blockIdx.x;
  int d = threadIdx.x * 4;
  float4 xv = *(const float4*)(xb + row * DDD + d);
  float ss = xv.x * xv.x + xv.y * xv.y + xv.z * xv.z + xv.w * xv.w;
  ss = block_reduce_sum(ss, sm);
  if (threadIdx.x == 0) invn[row] = 1.f / fmaxf(sqrtf(ss), 1e-12f);
}

__global__ __launch_bounds__(1024) void pool_partial_k(const float* __restrict__ xb,
                                                       const float* __restrict__ mask,
                                                       const float* __restrict__ invn,
                                                       float* __restrict__ partial) {
  int b = blockIdx.x, c = blockIdx.y, d = threadIdx.x;
  float s = 0.f;
  int nbeg = c * 64;
  for (int n = nbeg; n < nbeg + 64; ++n) {
    size_t r = (size_t)b * NNN + n;
    s += xb[r * DDD + d] * mask[r] * invn[r];
  }
  partial[((size_t)b * 16 + c) * DDD + d] = s;
}

__global__ __launch_bounds__(1024) void pool_final_k(const float* __restrict__ xb,
                                                     const float* __restrict__ mask,
                                                     const float* __restrict__ invn,
                                                     const float* __restrict__ partial,
                                                     float* __restrict__ out) {
  __shared__ float sm[16];
  int b = blockIdx.x, d = threadIdx.x;
  float msum = mask[(size_t)b * NNN + d];
  msum = block_reduce_sum(msum, sm);
  int len = (int)(msum + 0.5f);
  float s = 0.f;
#pragma unroll
  for (int c = 0; c < 16; ++c) s += partial[((size_t)b * 16 + c) * DDD + d];
  float avg = s / (float)len;
  size_t lr = (size_t)b * NNN + (len - 1);
  float last = xb[lr * DDD + d] * invn[lr];
  float pooled = 0.5f * (last + avg);
  float ssq = block_reduce_sum(pooled * pooled, sm);
  out[(size_t)b * DDD + d] = pooled / fmaxf(sqrtf(ssq), 1e-12f);
}

// ---------------- launch ----------------------------------------------------
extern "C" void kernel_launch(void* const* d_in, const int* in_sizes, int n_in,
                              void* d_out, int out_size, void* d_ws, size_t ws_size,
                              hipStream_t stream) {
  const float* x      = (const float*)d_in[0];
  const int*   ts     = (const int*)d_in[1];
  const float* mask   = (const float*)d_in[2];
  const float* ln1_g  = (const float*)d_in[3];
  const float* ln1_b  = (const float*)d_in[4];
  const float* w_uvqk = (const float*)d_in[5];
  const float* b_uvqk = (const float*)d_in[6];
  const float* ln2_g  = (const float*)d_in[7];
  const float* ln2_b  = (const float*)d_in[8];
  const float* w_o    = (const float*)d_in[9];
  const float* b_o    = (const float*)d_in[10];
  const float* pos_w  = (const float*)d_in[11];
  const float* ts_w   = (const float*)d_in[12];
  float* out = (float*)d_out;

  float* ws = (float*)d_ws;
  const size_t SZ = (size_t)BB * NNN * DDD;            // 8M
  float* xb   = ws;                                     // 8M f
  float* buf1 = ws + SZ;                                // 8M f (o)
  float* ubuf = ws + 2 * SZ;                            // 8M f (u)
  ushort* hbf = (ushort*)(ws + 3 * SZ);                 // 8M bf16
  ushort* wuT = hbf + SZ;                               // 8M bf16
  ushort* woT = wuT + 2 * (size_t)DDD * CCC;            // 2M bf16
  ushort* qkvb = woT + 2 * (size_t)DDD * DDD;           // 8192*3072 bf16
  ushort* vtb  = qkvb + (size_t)BB * NNN * 3072;        // 64*128*1024 bf16
  ushort* rabb = vtb + (size_t)BB * HHH * DVV * NNN;    // 8*1024*1024 bf16
  float* invn = (float*)(rabb + (size_t)BB * NNN * NNN);
  float* partial = invn + (size_t)BB * NNN;

  mask_x_k<<<(BB * NNN * DDD / 4) / 256, 256, 0, stream>>>(x, mask, xb);

  for (int l = 0; l < 2; ++l) {
    wconv_k<<<dim3(DDD / 32, CCC / 32), 256, 0, stream>>>(
        w_uvqk + (size_t)l * DDD * CCC, wuT + (size_t)l * CCC * DDD, DDD, CCC);
    wconv_k<<<dim3(DDD / 32, DDD / 32), 256, 0, stream>>>(
        w_o + (size_t)l * DDD * DDD, woT + (size_t)l * DDD * DDD, DDD, DDD);
  }

  rab_k<<<dim3(8, 8, BB), 256, 0, stream>>>(ts, pos_w, ts_w, rabb);

  for (int l = 0; l < 2; ++l) {
    ln_k<<<BB * NNN, 256, 0, stream>>>(xb, ln1_g + l * DDD, ln1_b + l * DDD,
                                       nullptr, 0, hbf);
    gemm_bf_k<2><<<dim3(CCC / 128, BB * NNN / 128), 256, 0, stream>>>(
        hbf, wuT + (size_t)l * CCC * DDD, b_uvqk + (size_t)l * CCC,
        ubuf, qkvb, DDD, CCC);
    vt_k<<<dim3(NNN / 32, DVV / 32, BB * HHH), 256, 0, stream>>>(qkvb, vtb);
    attn_mfma_k<<<dim3(NNN / 64, HHH, BB), 256, 0, stream>>>(
        qkvb, vtb, rabb, mask, buf1);
    ln_k<<<BB * NNN, 256, 0, stream>>>(buf1, ln2_g + l * DDD, ln2_b + l * DDD,
                                       ubuf, DDD, hbf);
    gemm_bf_k<1><<<dim3(DDD / 128, BB * NNN / 128), 256, 0, stream>>>(
        hbf, woT + (size_t)l * DDD * DDD, b_o + (size_t)l * DDD,
        xb, nullptr, DDD, DDD);
  }

  row_stats_k<<<BB * NNN, 256, 0, stream>>>(xb, invn);
  pool_partial_k<<<dim3(BB, 16), 1024, 0, stream>>>(xb, mask, invn, partial);
  pool_final_k<<<BB, 1024, 0, stream>>>(xb, mask, invn, partial, out);
}

// Round 5
// 704.007 us; speedup vs baseline: 4.6254x; 1.0431x over previous
//
#include <hip/hip_runtime.h>
#include <hip/hip_bf16.h>
#include <cstdint>
#include <cstddef>

// ---------------------------------------------------------------------------
// Round 5: length-based dead-work skipping. Rows n >= length[b] never affect
// the output (pooling masks them; attention masks keys). len[b] computed on
// device; row-blocks fully above len early-exit in gemm/ln/vt/attn/rab.
// Live rows bit-identical to round 4.
// ---------------------------------------------------------------------------

#define BB   8
#define NNN  1024
#define DDD  1024
#define HHH  8
#define DVV  128
#define CCC  4096
#define TBK  128

typedef __bf16 bf8_t  __attribute__((ext_vector_type(8)));
typedef float  f4_t   __attribute__((ext_vector_type(4)));

__device__ __forceinline__ float bf2f(ushort u) {
  union { uint i; float f; } v; v.i = ((uint)u) << 16; return v.f;
}
__device__ __forceinline__ ushort f2bf(float f) {
  __hip_bfloat16 h = __float2bfloat16(f);
  return *(ushort*)&h;
}

// ---------------- block reduce (blockDim 256 or 1024) ----------------------
__device__ __forceinline__ float block_reduce_sum(float v, float* sm) {
#pragma unroll
  for (int o = 32; o > 0; o >>= 1) v += __shfl_down(v, o, 64);
  int lane = threadIdx.x & 63;
  int wid  = threadIdx.x >> 6;
  __syncthreads();
  if (lane == 0) sm[wid] = v;
  __syncthreads();
  int nw = blockDim.x >> 6;
  float r = (threadIdx.x < nw) ? sm[threadIdx.x] : 0.f;
#pragma unroll
  for (int o = 8; o > 0; o >>= 1) r += __shfl_down(r, o, 64);
  if (threadIdx.x == 0) sm[0] = r;
  __syncthreads();
  return sm[0];
}

// ---------------- len[b] = round(sum(mask[b,:])) ----------------------------
__global__ __launch_bounds__(1024) void len_k(const float* __restrict__ mask,
                                              int* __restrict__ lenp) {
  __shared__ float sm[16];
  int b = blockIdx.x;
  float m = mask[(size_t)b * NNN + threadIdx.x];
  float s = block_reduce_sum(m, sm);
  if (threadIdx.x == 0) lenp[b] = (int)(s + 0.5f);
}

// ---------------- x = x * mask ---------------------------------------------
__global__ __launch_bounds__(256) void mask_x_k(const float* __restrict__ x,
                                                const float* __restrict__ mask,
                                                float* __restrict__ xb) {
  size_t i4 = (size_t)blockIdx.x * 256 + threadIdx.x;
  size_t row = i4 >> 8;
  float m = mask[row];
  float4 v = ((const float4*)x)[i4];
  v.x *= m; v.y *= m; v.z *= m; v.w *= m;
  ((float4*)xb)[i4] = v;
}

// ---------------- weight transpose + bf16 convert ---------------------------
__global__ __launch_bounds__(256) void wconv_k(const float* __restrict__ W,
                                               ushort* __restrict__ Wt,
                                               int K, int Nn) {
  __shared__ float t[32][33];
  int k0 = blockIdx.x * 32, n0 = blockIdx.y * 32;
  int tx = threadIdx.x & 31, ty = threadIdx.x >> 5;
  for (int r = ty; r < 32; r += 8)
    t[r][tx] = W[(size_t)(k0 + r) * Nn + n0 + tx];
  __syncthreads();
  for (int r = ty; r < 32; r += 8)
    Wt[(size_t)(n0 + r) * K + k0 + tx] = f2bf(t[tx][r]);
}

// ---------------- rab precompute -------------------------------------------
__global__ __launch_bounds__(256) void rab_k(const int* __restrict__ ts,
                                             const float* __restrict__ pos_w,
                                             const float* __restrict__ ts_w,
                                             const int* __restrict__ lenp,
                                             ushort* __restrict__ rabb) {
  int jt = blockIdx.x, it = blockIdx.y, b = blockIdx.z;
  if (jt > it) return;
  int len = lenp[b];
  if (it * 128 >= len || jt * 128 >= len) return;   // tile fully dead
  int j = jt * 128 + (threadIdx.x & 127);
  int half = threadIdx.x >> 7;
  int tsj = ts[(size_t)b * NNN + j];
  for (int rr = 0; rr < 64; ++rr) {
    int i = it * 128 + rr * 2 + half;
    int ii = i + 1; if (ii > NNN - 1) ii = NNN - 1;
    int tsi = ts[(size_t)b * NNN + ii];
    float af = fabsf((float)(tsi - tsj));
    af = fmaxf(af, 1.f);
    int bkt = (int)__log2f(af);
    bkt = min(max(bkt, 0), TBK);
    float rab = pos_w[i - j + NNN - 1] + ts_w[bkt];
    rabb[((size_t)b * NNN + i) * NNN + j] = f2bf(rab);
  }
}

// ---------------- LayerNorm (optionally * u), bf16 output -------------------
__global__ __launch_bounds__(256) void ln_k(const float* __restrict__ X,
                                            const float* __restrict__ g,
                                            const float* __restrict__ bsh,
                                            const float* __restrict__ umat,
                                            int ustride,
                                            const int* __restrict__ lenp,
                                            ushort* __restrict__ Y) {
  __shared__ float sm[16];
  size_t row = blockIdx.x;
  if (((int)row & 1023) >= lenp[row >> 10]) return;   // dead row
  const float* xr = X + row * DDD;
  int d = threadIdx.x * 4;
  float4 xv = *(const float4*)(xr + d);
  float s = xv.x + xv.y + xv.z + xv.w;
  s = block_reduce_sum(s, sm);
  float mu = s * (1.f / 1024.f);
  float d0 = xv.x - mu, d1 = xv.y - mu, d2 = xv.z - mu, d3 = xv.w - mu;
  float ss = d0 * d0 + d1 * d1 + d2 * d2 + d3 * d3;
  ss = block_reduce_sum(ss, sm);
  float rs = rsqrtf(ss * (1.f / 1024.f) + 1e-6f);
  float y0 = d0 * rs * g[d + 0] + bsh[d + 0];
  float y1 = d1 * rs * g[d + 1] + bsh[d + 1];
  float y2 = d2 * rs * g[d + 2] + bsh[d + 2];
  float y3 = d3 * rs * g[d + 3] + bsh[d + 3];
  if (umat != nullptr) {
    const float* ur = umat + row * (size_t)ustride + d;
    y0 *= ur[0]; y1 *= ur[1]; y2 *= ur[2]; y3 *= ur[3];
  }
  ushort tmp[4] = { f2bf(y0), f2bf(y1), f2bf(y2), f2bf(y3) };
  *(uint2*)(Y + row * DDD + d) = *(uint2*)tmp;
}

// ---------------- bf16 MFMA GEMM -------------------------------------------
// MODE 1: C[row*Nn+col] += z (+bias)            (w_o GEMM, Nn=1024)
// MODE 2: uvqk split: col<1024 -> C (u fp32), col>=1024 -> Cb (qkv bf16)
template <int MODE>
__global__ __launch_bounds__(256) void gemm_bf_k(const ushort* __restrict__ A,
                                                 const ushort* __restrict__ Bt,
                                                 const float* __restrict__ bias,
                                                 float* __restrict__ C,
                                                 ushort* __restrict__ Cb,
                                                 const int* __restrict__ lenp,
                                                 int K, int Nn) {
  __shared__ alignas(16) ushort As[128 * 32];
  __shared__ alignas(16) ushort Bs[128 * 32];
  int m0 = blockIdx.y * 128, n0 = blockIdx.x * 128;
  if ((m0 & 1023) >= lenp[m0 >> 10]) return;   // all 128 rows dead
  int tid = threadIdx.x;
  int wave = tid >> 6, lane = tid & 63;
  int quad = lane >> 4, l16 = lane & 15;
  int wm = wave >> 1, wn = wave & 1;

  f4_t acc[4][4] = {};

  int r_l = tid >> 2;
  int p   = tid & 3;

  for (int k0 = 0; k0 < K; k0 += 32) {
    __syncthreads();
#pragma unroll
    for (int g = 0; g < 2; ++g) {
      int row = g * 64 + r_l;
      int q = (p - (row >> 1)) & 3;
      __builtin_amdgcn_global_load_lds(
          (const __attribute__((address_space(1))) void*)(A + (size_t)(m0 + row) * K + k0 + q * 8),
          (__attribute__((address_space(3))) void*)(As + (g * 64 + wave * 16) * 32),
          16, 0, 0);
      __builtin_amdgcn_global_load_lds(
          (const __attribute__((address_space(1))) void*)(Bt + (size_t)(n0 + row) * K + k0 + q * 8),
          (__attribute__((address_space(3))) void*)(Bs + (g * 64 + wave * 16) * 32),
          16, 0, 0);
    }
    __syncthreads();

    bf8_t af[4], bfr[4];
#pragma unroll
    for (int t = 0; t < 4; ++t) {
      int row = wm * 64 + t * 16 + l16;
      af[t] = *(const bf8_t*)&As[row * 32 + ((quad + (row >> 1)) & 3) * 8];
      int col = wn * 64 + t * 16 + l16;
      bfr[t] = *(const bf8_t*)&Bs[col * 32 + ((quad + (col >> 1)) & 3) * 8];
    }
#pragma unroll
    for (int i = 0; i < 4; ++i)
#pragma unroll
      for (int j = 0; j < 4; ++j)
        acc[i][j] = __builtin_amdgcn_mfma_f32_16x16x32_bf16(af[i], bfr[j],
                                                            acc[i][j], 0, 0, 0);
  }

#pragma unroll
  for (int j = 0; j < 4; ++j) {
    int col = n0 + wn * 64 + j * 16 + l16;
    float bz = bias[col];
#pragma unroll
    for (int i = 0; i < 4; ++i) {
      int rbase = m0 + wm * 64 + i * 16 + quad * 4;
#pragma unroll
      for (int r = 0; r < 4; ++r) {
        float z = acc[i][j][r] + bz;
        int row = rbase + r;
        if (MODE == 1) {
          C[(size_t)row * Nn + col] += z;
        } else {
          float s = z / (1.f + __expf(-z));
          if (col < 1024) C[(size_t)row * 1024 + col] = s;
          else Cb[(size_t)row * 3072 + (col - 1024)] = f2bf(s);
        }
      }
    }
  }
}

// ---------------- V transpose: qkv v-part [n][h*128+dv] -> vt[b,h,dv,n] -----
__global__ __launch_bounds__(256) void vt_k(const ushort* __restrict__ qkv,
                                            const int* __restrict__ lenp,
                                            ushort* __restrict__ vt) {
  __shared__ ushort t[32][33];
  int bh = blockIdx.z; int b = bh >> 3, h = bh & 7;
  int nt = blockIdx.x * 32, dt = blockIdx.y * 32;
  if (nt >= lenp[b]) return;                    // dead key rows
  int tx = threadIdx.x & 31, ty = threadIdx.x >> 5;
  for (int rr = ty; rr < 32; rr += 8)
    t[rr][tx] = qkv[(size_t)(b * NNN + nt + rr) * 3072 + h * 128 + dt + tx];
  __syncthreads();
  for (int rr = ty; rr < 32; rr += 8)
    vt[((size_t)bh * 128 + dt + rr) * NNN + nt + tx] = t[tx][rr];
}

// ---------------- MFMA flash attention --------------------------------------
__global__ __launch_bounds__(256, 4) void attn_mfma_k(
    const ushort* __restrict__ qkv, const ushort* __restrict__ vt,
    const ushort* __restrict__ rabb, const float* __restrict__ mask,
    const int* __restrict__ lenp, float* __restrict__ o) {
  __shared__ alignas(16) ushort Ks[64 * 128];   // 16 KB
  __shared__ alignas(16) ushort Vs[128 * 64];   // 16 KB
  __shared__ alignas(16) ushort Ps[64 * 64];    // 8 KB
  int h = blockIdx.y, b = blockIdx.z;
  int qt = ((int)blockIdx.x + (int)blockIdx.y + 2 * (int)blockIdx.z) & 15;
  int n0 = qt * 64;
  if (n0 >= lenp[b]) return;                    // dead query tile
  int tid = threadIdx.x, w = tid >> 6, lane = tid & 63;
  int quad = lane >> 4, l16 = lane & 15;

  // ---- stage Q (64x128) through Ks, move to regs ----
  const ushort* qg0 = qkv + ((size_t)(b * NNN + n0)) * 3072 + 1024 + h * 128;
#pragma unroll
  for (int t = 0; t < 4; ++t) {
    int lrow = w * 16 + t * 4 + (lane >> 4);
    int q = ((lane & 15) - lrow) & 15;
    __builtin_amdgcn_global_load_lds(
        (const __attribute__((address_space(1))) void*)(qg0 + (size_t)lrow * 3072 + q * 8),
        (__attribute__((address_space(3))) void*)(Ks + (w * 16 + t * 4) * 128),
        16, 0, 0);
  }
  __syncthreads();
  bf8_t qf[4];
  {
    int lr = w * 16 + l16;
#pragma unroll
    for (int kk = 0; kk < 4; ++kk)
      qf[kk] = *(const bf8_t*)&Ks[lr * 128 + (((kk * 4 + quad) + lr) & 15) * 8];
  }

  f4_t oacc[8] = {};
  const ushort* kg0 = qkv + (size_t)b * NNN * 3072 + 2048 + h * 128;
  const ushort* vg0 = vt + (size_t)(b * 8 + h) * 128 * NNN;
  const ushort* rb0 = rabb + ((size_t)(b * NNN + n0 + w * 16 + quad * 4)) * NNN;
  const float* mk0 = mask + (size_t)b * NNN;
  int mtmax = qt + 1;

  for (int mt = 0; mt < mtmax; ++mt) {
    int m0 = mt * 64;
    __syncthreads();
    // stage K tile (64 rows x 128 k)
#pragma unroll
    for (int t = 0; t < 4; ++t) {
      int lrow = w * 16 + t * 4 + (lane >> 4);
      int q = ((lane & 15) - lrow) & 15;
      __builtin_amdgcn_global_load_lds(
          (const __attribute__((address_space(1))) void*)(kg0 + (size_t)(m0 + lrow) * 3072 + q * 8),
          (__attribute__((address_space(3))) void*)(Ks + (w * 16 + t * 4) * 128),
          16, 0, 0);
    }
    // stage V^T tile (128 dv x 64 m)
#pragma unroll
    for (int t = 0; t < 4; ++t) {
      int dv = w * 32 + t * 8 + (lane >> 3);
      int q = ((lane & 7) - dv) & 7;
      __builtin_amdgcn_global_load_lds(
          (const __attribute__((address_space(1))) void*)(vg0 + (size_t)dv * NNN + m0 + q * 8),
          (__attribute__((address_space(3))) void*)(Vs + (w * 32 + t * 8) * 64),
          16, 0, 0);
    }
    // rab prefetch into registers
    ushort rv[4][4];
#pragma unroll
    for (int tj = 0; tj < 4; ++tj)
#pragma unroll
      for (int r = 0; r < 4; ++r)
        rv[tj][r] = rb0[(size_t)r * NNN + m0 + tj * 16 + l16];
    __syncthreads();

    // ---- S = Q K^T (per wave: 16q x 64m) ----
    f4_t sacc[4] = {};
#pragma unroll
    for (int kk = 0; kk < 4; ++kk) {
      bf8_t kf[4];
#pragma unroll
      for (int tj = 0; tj < 4; ++tj) {
        int lr = tj * 16 + l16;
        kf[tj] = *(const bf8_t*)&Ks[lr * 128 + (((kk * 4 + quad) + lr) & 15) * 8];
      }
#pragma unroll
      for (int tj = 0; tj < 4; ++tj)
        sacc[tj] = __builtin_amdgcn_mfma_f32_16x16x32_bf16(qf[kk], kf[tj],
                                                           sacc[tj], 0, 0, 0);
    }

    // ---- P = silu(S + rab)/N * causal * mask -> Ps ----
#pragma unroll
    for (int tj = 0; tj < 4; ++tj) {
      int m = tj * 16 + l16;
      int gj = m0 + m;
      float msc = mk0[gj] * (1.f / 1024.f);
#pragma unroll
      for (int r = 0; r < 4; ++r) {
        int q = w * 16 + quad * 4 + r;
        int gi = n0 + q;
        float z = sacc[tj][r] + bf2f(rv[tj][r]);
        float pp = z / (1.f + __expf(-z)) * msc;
        if (gj > gi) pp = 0.f;
        Ps[q * 64 + (((m >> 3) + q) & 7) * 8 + (m & 7)] = f2bf(pp);
      }
    }

    // ---- O += P V ----
#pragma unroll
    for (int kk = 0; kk < 2; ++kk) {
      bf8_t pf, vf[8];
      {
        int q = w * 16 + l16;
        pf = *(const bf8_t*)&Ps[q * 64 + (((kk * 4 + quad) + q) & 7) * 8];
      }
#pragma unroll
      for (int tj = 0; tj < 8; ++tj) {
        int dv = tj * 16 + l16;
        vf[tj] = *(const bf8_t*)&Vs[dv * 64 + (((kk * 4 + quad) + dv) & 7) * 8];
      }
#pragma unroll
      for (int tj = 0; tj < 8; ++tj)
        oacc[tj] = __builtin_amdgcn_mfma_f32_16x16x32_bf16(pf, vf[tj],
                                                           oacc[tj], 0, 0, 0);
    }
  }

  // ---- store O ----
#pragma unroll
  for (int tj = 0; tj < 8; ++tj) {
    int col = h * 128 + tj * 16 + l16;
#pragma unroll
    for (int r = 0; r < 4; ++r) {
      int gi = n0 + w * 16 + quad * 4 + r;
      o[((size_t)(b * NNN + gi)) * DDD + col] = oacc[tj][r];
    }
  }
}

// ---------------- pooling ---------------------------------------------------
__global__ __launch_bounds__(256) void row_stats_k(const float* __restrict__ xb,
                                                   const int* __restrict__ lenp,
                                                   float* __restrict__ invn) {
  __shared__ float sm[16];
  size_t row = blockIdx.x;
  if (((int)row & 1023) >= lenp[row >> 10]) return;
  int d = threadIdx.x * 4;
  float4 xv = *(const float4*)(xb + row * DDD + d);
  float ss = xv.x * xv.x + xv.y * xv.y + xv.z * xv.z + xv.w * xv.w;
  ss = block_reduce_sum(ss, sm);
  if (threadIdx.x == 0) invn[row] = 1.f / fmaxf(sqrtf(ss), 1e-12f);
}

__global__ __launch_bounds__(1024) void pool_partial_k(const float* __restrict__ xb,
                                                       const float* __restrict__ mask,
                                                       const float* __restrict__ invn,
                                                       const int* __restrict__ lenp,
                                                       float* __restrict__ partial) {
  int b = blockIdx.x, c = blockIdx.y, d = threadIdx.x;
  int len = lenp[b];
  float s = 0.f;
  int nbeg = c * 64;
  int nend = min(nbeg + 64, len);
  for (int n = nbeg; n < nend; ++n) {
    size_t r = (size_t)b * NNN + n;
    s += xb[r * DDD + d] * invn[r];
  }
  partial[((size_t)b * 16 + c) * DDD + d] = s;
}

__global__ __launch_bounds__(1024) void pool_final_k(const float* __restrict__ xb,
                                                     const float* __restrict__ invn,
                                                     const float* __restrict__ partial,
                                                     const int* __restrict__ lenp,
                                                     float* __restrict__ out) {
  __shared__ float sm[16];
  int b = blockIdx.x, d = threadIdx.x;
  int len = lenp[b];
  float s = 0.f;
#pragma unroll
  for (int c = 0; c < 16; ++c) s += partial[((size_t)b * 16 + c) * DDD + d];
  float avg = s / (float)len;
  size_t lr = (size_t)b * NNN + (len - 1);
  float last = xb[lr * DDD + d] * invn[lr];
  float pooled = 0.5f * (last + avg);
  float ssq = block_reduce_sum(pooled * pooled, sm);
  out[(size_t)b * DDD + d] = pooled / fmaxf(sqrtf(ssq), 1e-12f);
}

// ---------------- launch ----------------------------------------------------
extern "C" void kernel_launch(void* const* d_in, const int* in_sizes, int n_in,
                              void* d_out, int out_size, void* d_ws, size_t ws_size,
                              hipStream_t stream) {
  const float* x      = (const float*)d_in[0];
  const int*   ts     = (const int*)d_in[1];
  const float* mask   = (const float*)d_in[2];
  const float* ln1_g  = (const float*)d_in[3];
  const float* ln1_b  = (const float*)d_in[4];
  const float* w_uvqk = (const float*)d_in[5];
  const float* b_uvqk = (const float*)d_in[6];
  const float* ln2_g  = (const float*)d_in[7];
  const float* ln2_b  = (const float*)d_in[8];
  const float* w_o    = (const float*)d_in[9];
  const float* b_o    = (const float*)d_in[10];
  const float* pos_w  = (const float*)d_in[11];
  const float* ts_w   = (const float*)d_in[12];
  float* out = (float*)d_out;

  float* ws = (float*)d_ws;
  const size_t SZ = (size_t)BB * NNN * DDD;            // 8M
  float* xb   = ws;                                     // 8M f
  float* buf1 = ws + SZ;                                // 8M f (o)
  float* ubuf = ws + 2 * SZ;                            // 8M f (u)
  ushort* hbf = (ushort*)(ws + 3 * SZ);                 // 8M bf16
  ushort* wuT = hbf + SZ;                               // 8M bf16
  ushort* woT = wuT + 2 * (size_t)DDD * CCC;            // 2M bf16
  ushort* qkvb = woT + 2 * (size_t)DDD * DDD;           // 8192*3072 bf16
  ushort* vtb  = qkvb + (size_t)BB * NNN * 3072;        // 64*128*1024 bf16
  ushort* rabb = vtb + (size_t)BB * HHH * DVV * NNN;    // 8*1024*1024 bf16
  float* invn = (float*)(rabb + (size_t)BB * NNN * NNN);
  float* partial = invn + (size_t)BB * NNN;
  int* lenp = (int*)(partial + (size_t)BB * 16 * DDD);

  mask_x_k<<<(BB * NNN * DDD / 4) / 256, 256, 0, stream>>>(x, mask, xb);
  len_k<<<BB, 1024, 0, stream>>>(mask, lenp);

  for (int l = 0; l < 2; ++l) {
    wconv_k<<<dim3(DDD / 32, CCC / 32), 256, 0, stream>>>(
        w_uvqk + (size_t)l * DDD * CCC, wuT + (size_t)l * CCC * DDD, DDD, CCC);
    wconv_k<<<dim3(DDD / 32, DDD / 32), 256, 0, stream>>>(
        w_o + (size_t)l * DDD * DDD, woT + (size_t)l * DDD * DDD, DDD, DDD);
  }

  rab_k<<<dim3(8, 8, BB), 256, 0, stream>>>(ts, pos_w, ts_w, lenp, rabb);

  for (int l = 0; l < 2; ++l) {
    ln_k<<<BB * NNN, 256, 0, stream>>>(xb, ln1_g + l * DDD, ln1_b + l * DDD,
                                       nullptr, 0, lenp, hbf);
    gemm_bf_k<2><<<dim3(CCC / 128, BB * NNN / 128), 256, 0, stream>>>(
        hbf, wuT + (size_t)l * CCC * DDD, b_uvqk + (size_t)l * CCC,
        ubuf, qkvb, lenp, DDD, CCC);
    vt_k<<<dim3(NNN / 32, DVV / 32, BB * HHH), 256, 0, stream>>>(qkvb, lenp, vtb);
    attn_mfma_k<<<dim3(NNN / 64, HHH, BB), 256, 0, stream>>>(
        qkvb, vtb, rabb, mask, lenp, buf1);
    ln_k<<<BB * NNN, 256, 0, stream>>>(buf1, ln2_g + l * DDD, ln2_b + l * DDD,
                                       ubuf, DDD, lenp, hbf);
    gemm_bf_k<1><<<dim3(DDD / 128, BB * NNN / 128), 256, 0, stream>>>(
        hbf, woT + (size_t)l * DDD * DDD, b_o + (size_t)l * DDD,
        xb, nullptr, lenp, DDD, DDD);
  }

  row_stats_k<<<BB * NNN, 256, 0, stream>>>(xb, lenp, invn);
  pool_partial_k<<<dim3(BB, 16), 1024, 0, stream>>>(xb, mask, invn, lenp, partial);
  pool_final_k<<<BB, 1024, 0, stream>>>(xb, invn, partial, lenp, out);
}

// Round 6
// 670.030 us; speedup vs baseline: 4.8599x; 1.0507x over previous
//
#include <hip/hip_runtime.h>
#include <hip/hip_bf16.h>
#include <cstdint>
#include <cstddef>

// ---------------------------------------------------------------------------
// Round 6: BK=64 GEMM (two BK=32 panels, half the barrier drains), vt fused
// into gemm<2> epilogue (V written directly transposed; q/k in slim 2048-
// stride buffer), mask_x fused into layer-0 LN. Arithmetic identical to r5.
// ---------------------------------------------------------------------------

#define BB   8
#define NNN  1024
#define DDD  1024
#define HHH  8
#define DVV  128
#define CCC  4096
#define TBK  128

typedef __bf16 bf8_t  __attribute__((ext_vector_type(8)));
typedef float  f4_t   __attribute__((ext_vector_type(4)));

__device__ __forceinline__ float bf2f(ushort u) {
  union { uint i; float f; } v; v.i = ((uint)u) << 16; return v.f;
}
__device__ __forceinline__ ushort f2bf(float f) {
  __hip_bfloat16 h = __float2bfloat16(f);
  return *(ushort*)&h;
}

// ---------------- block reduce (blockDim 256 or 1024) ----------------------
__device__ __forceinline__ float block_reduce_sum(float v, float* sm) {
#pragma unroll
  for (int o = 32; o > 0; o >>= 1) v += __shfl_down(v, o, 64);
  int lane = threadIdx.x & 63;
  int wid  = threadIdx.x >> 6;
  __syncthreads();
  if (lane == 0) sm[wid] = v;
  __syncthreads();
  int nw = blockDim.x >> 6;
  float r = (threadIdx.x < nw) ? sm[threadIdx.x] : 0.f;
#pragma unroll
  for (int o = 8; o > 0; o >>= 1) r += __shfl_down(r, o, 64);
  if (threadIdx.x == 0) sm[0] = r;
  __syncthreads();
  return sm[0];
}

// ---------------- len[b] ----------------------------------------------------
__global__ __launch_bounds__(1024) void len_k(const float* __restrict__ mask,
                                              int* __restrict__ lenp) {
  __shared__ float sm[16];
  int b = blockIdx.x;
  float m = mask[(size_t)b * NNN + threadIdx.x];
  float s = block_reduce_sum(m, sm);
  if (threadIdx.x == 0) lenp[b] = (int)(s + 0.5f);
}

// ---------------- weight transpose + bf16 convert ---------------------------
__global__ __launch_bounds__(256) void wconv_k(const float* __restrict__ W,
                                               ushort* __restrict__ Wt,
                                               int K, int Nn) {
  __shared__ float t[32][33];
  int k0 = blockIdx.x * 32, n0 = blockIdx.y * 32;
  int tx = threadIdx.x & 31, ty = threadIdx.x >> 5;
  for (int r = ty; r < 32; r += 8)
    t[r][tx] = W[(size_t)(k0 + r) * Nn + n0 + tx];
  __syncthreads();
  for (int r = ty; r < 32; r += 8)
    Wt[(size_t)(n0 + r) * K + k0 + tx] = f2bf(t[tx][r]);
}

// ---------------- rab precompute -------------------------------------------
__global__ __launch_bounds__(256) void rab_k(const int* __restrict__ ts,
                                             const float* __restrict__ pos_w,
                                             const float* __restrict__ ts_w,
                                             const int* __restrict__ lenp,
                                             ushort* __restrict__ rabb) {
  int jt = blockIdx.x, it = blockIdx.y, b = blockIdx.z;
  if (jt > it) return;
  int len = lenp[b];
  if (it * 128 >= len || jt * 128 >= len) return;
  int j = jt * 128 + (threadIdx.x & 127);
  int half = threadIdx.x >> 7;
  int tsj = ts[(size_t)b * NNN + j];
  for (int rr = 0; rr < 64; ++rr) {
    int i = it * 128 + rr * 2 + half;
    int ii = i + 1; if (ii > NNN - 1) ii = NNN - 1;
    int tsi = ts[(size_t)b * NNN + ii];
    float af = fabsf((float)(tsi - tsj));
    af = fmaxf(af, 1.f);
    int bkt = (int)__log2f(af);
    bkt = min(max(bkt, 0), TBK);
    float rab = pos_w[i - j + NNN - 1] + ts_w[bkt];
    rabb[((size_t)b * NNN + i) * NNN + j] = f2bf(rab);
  }
}

// ---------------- LayerNorm. FIRST=1: also copy x -> xb (layer-0 fusion) ----
template <int FIRST>
__global__ __launch_bounds__(256) void ln_k(const float* __restrict__ X,
                                            const float* __restrict__ g,
                                            const float* __restrict__ bsh,
                                            const float* __restrict__ umat,
                                            int ustride,
                                            const int* __restrict__ lenp,
                                            float* __restrict__ xb,
                                            ushort* __restrict__ Y) {
  __shared__ float sm[16];
  size_t row = blockIdx.x;
  if (((int)row & 1023) >= lenp[row >> 10]) return;
  const float* xr = X + row * DDD;
  int d = threadIdx.x * 4;
  float4 xv = *(const float4*)(xr + d);
  if (FIRST) *(float4*)(xb + row * DDD + d) = xv;   // xb = x (mask==1 live)
  float s = xv.x + xv.y + xv.z + xv.w;
  s = block_reduce_sum(s, sm);
  float mu = s * (1.f / 1024.f);
  float d0 = xv.x - mu, d1 = xv.y - mu, d2 = xv.z - mu, d3 = xv.w - mu;
  float ss = d0 * d0 + d1 * d1 + d2 * d2 + d3 * d3;
  ss = block_reduce_sum(ss, sm);
  float rs = rsqrtf(ss * (1.f / 1024.f) + 1e-6f);
  float y0 = d0 * rs * g[d + 0] + bsh[d + 0];
  float y1 = d1 * rs * g[d + 1] + bsh[d + 1];
  float y2 = d2 * rs * g[d + 2] + bsh[d + 2];
  float y3 = d3 * rs * g[d + 3] + bsh[d + 3];
  if (umat != nullptr) {
    const float* ur = umat + row * (size_t)ustride + d;
    y0 *= ur[0]; y1 *= ur[1]; y2 *= ur[2]; y3 *= ur[3];
  }
  ushort tmp[4] = { f2bf(y0), f2bf(y1), f2bf(y2), f2bf(y3) };
  *(uint2*)(Y + row * DDD + d) = *(uint2*)tmp;
}

// ---------------- bf16 MFMA GEMM, BK=64 (two BK=32 panels) ------------------
// MODE 1: C[row*Nn+col] += z (+bias)            (w_o GEMM, Nn=1024)
// MODE 2: uvqk split by 1024-col region:
//   region 0: u -> C fp32 (stride 1024)
//   region 1: v -> Vt[b,h,dv,n] bf16 DIRECT TRANSPOSED (packed ushort4)
//   region 2/3: q,k -> Qk bf16 (stride 2048, offset col-2048)
template <int MODE>
__global__ __launch_bounds__(256) void gemm_bf_k(const ushort* __restrict__ A,
                                                 const ushort* __restrict__ Bt,
                                                 const float* __restrict__ bias,
                                                 float* __restrict__ C,
                                                 ushort* __restrict__ Qk,
                                                 ushort* __restrict__ Vt,
                                                 const int* __restrict__ lenp,
                                                 int K, int Nn) {
  __shared__ alignas(16) ushort As[2 * 128 * 32];
  __shared__ alignas(16) ushort Bs[2 * 128 * 32];
  int m0 = blockIdx.y * 128, n0 = blockIdx.x * 128;
  if ((m0 & 1023) >= lenp[m0 >> 10]) return;
  int tid = threadIdx.x;
  int wave = tid >> 6, lane = tid & 63;
  int quad = lane >> 4, l16 = lane & 15;
  int wm = wave >> 1, wn = wave & 1;

  f4_t acc[4][4] = {};

  int r_l = tid >> 2;      // row within 64-row group
  int p   = tid & 3;       // 16B chunk slot within 32-elem panel row

  for (int k0 = 0; k0 < K; k0 += 64) {
    __syncthreads();
#pragma unroll
    for (int s = 0; s < 2; ++s) {
#pragma unroll
      for (int g = 0; g < 2; ++g) {
        int row = g * 64 + r_l;
        int q = (p - (row >> 1)) & 3;
        __builtin_amdgcn_global_load_lds(
            (const __attribute__((address_space(1))) void*)(A + (size_t)(m0 + row) * K + k0 + s * 32 + q * 8),
            (__attribute__((address_space(3))) void*)(As + s * 4096 + (g * 64 + wave * 16) * 32),
            16, 0, 0);
        __builtin_amdgcn_global_load_lds(
            (const __attribute__((address_space(1))) void*)(Bt + (size_t)(n0 + row) * K + k0 + s * 32 + q * 8),
            (__attribute__((address_space(3))) void*)(Bs + s * 4096 + (g * 64 + wave * 16) * 32),
            16, 0, 0);
      }
    }
    __syncthreads();

#pragma unroll
    for (int s = 0; s < 2; ++s) {
      bf8_t af[4], bfr[4];
#pragma unroll
      for (int t = 0; t < 4; ++t) {
        int row = wm * 64 + t * 16 + l16;
        af[t] = *(const bf8_t*)&As[s * 4096 + row * 32 + ((quad + (row >> 1)) & 3) * 8];
        int col = wn * 64 + t * 16 + l16;
        bfr[t] = *(const bf8_t*)&Bs[s * 4096 + col * 32 + ((quad + (col >> 1)) & 3) * 8];
      }
#pragma unroll
      for (int i = 0; i < 4; ++i)
#pragma unroll
        for (int j = 0; j < 4; ++j)
          acc[i][j] = __builtin_amdgcn_mfma_f32_16x16x32_bf16(af[i], bfr[j],
                                                              acc[i][j], 0, 0, 0);
    }
  }

  int region = n0 >> 10;   // MODE 2 only; blocks never straddle 1024 cols
#pragma unroll
  for (int j = 0; j < 4; ++j) {
    int col = n0 + wn * 64 + j * 16 + l16;
    float bz = bias[col];
#pragma unroll
    for (int i = 0; i < 4; ++i) {
      int rbase = m0 + wm * 64 + i * 16 + quad * 4;
      if (MODE == 1) {
#pragma unroll
        for (int r = 0; r < 4; ++r)
          C[(size_t)(rbase + r) * Nn + col] += acc[i][j][r] + bz;
      } else if (region == 0) {
#pragma unroll
        for (int r = 0; r < 4; ++r) {
          float z = acc[i][j][r] + bz;
          C[(size_t)(rbase + r) * 1024 + col] = z / (1.f + __expf(-z));
        }
      } else if (region == 1) {
        int hd = col - 1024;
        int b = m0 >> 10, nl = rbase & 1023;
        ushort4 pk;
        float z;
        z = acc[i][j][0] + bz; pk.x = f2bf(z / (1.f + __expf(-z)));
        z = acc[i][j][1] + bz; pk.y = f2bf(z / (1.f + __expf(-z)));
        z = acc[i][j][2] + bz; pk.z = f2bf(z / (1.f + __expf(-z)));
        z = acc[i][j][3] + bz; pk.w = f2bf(z / (1.f + __expf(-z)));
        *(ushort4*)&Vt[((size_t)(b * 8 + (hd >> 7)) * 128 + (hd & 127)) * NNN + nl] = pk;
      } else {
#pragma unroll
        for (int r = 0; r < 4; ++r) {
          float z = acc[i][j][r] + bz;
          Qk[(size_t)(rbase + r) * 2048 + (col - 2048)] = f2bf(z / (1.f + __expf(-z)));
        }
      }
    }
  }
}

// ---------------- MFMA flash attention --------------------------------------
__global__ __launch_bounds__(256, 4) void attn_mfma_k(
    const ushort* __restrict__ qk, const ushort* __restrict__ vt,
    const ushort* __restrict__ rabb, const float* __restrict__ mask,
    const int* __restrict__ lenp, float* __restrict__ o) {
  __shared__ alignas(16) ushort Ks[64 * 128];   // 16 KB
  __shared__ alignas(16) ushort Vs[128 * 64];   // 16 KB
  __shared__ alignas(16) ushort Ps[64 * 64];    // 8 KB
  int h = blockIdx.y, b = blockIdx.z;
  int qt = ((int)blockIdx.x + (int)blockIdx.y + 2 * (int)blockIdx.z) & 15;
  int n0 = qt * 64;
  if (n0 >= lenp[b]) return;
  int tid = threadIdx.x, w = tid >> 6, lane = tid & 63;
  int quad = lane >> 4, l16 = lane & 15;

  // ---- stage Q (64x128) through Ks, move to regs ----
  const ushort* qg0 = qk + ((size_t)(b * NNN + n0)) * 2048 + h * 128;
#pragma unroll
  for (int t = 0; t < 4; ++t) {
    int lrow = w * 16 + t * 4 + (lane >> 4);
    int q = ((lane & 15) - lrow) & 15;
    __builtin_amdgcn_global_load_lds(
        (const __attribute__((address_space(1))) void*)(qg0 + (size_t)lrow * 2048 + q * 8),
        (__attribute__((address_space(3))) void*)(Ks + (w * 16 + t * 4) * 128),
        16, 0, 0);
  }
  __syncthreads();
  bf8_t qf[4];
  {
    int lr = w * 16 + l16;
#pragma unroll
    for (int kk = 0; kk < 4; ++kk)
      qf[kk] = *(const bf8_t*)&Ks[lr * 128 + (((kk * 4 + quad) + lr) & 15) * 8];
  }

  f4_t oacc[8] = {};
  const ushort* kg0 = qk + (size_t)b * NNN * 2048 + 1024 + h * 128;
  const ushort* vg0 = vt + (size_t)(b * 8 + h) * 128 * NNN;
  const ushort* rb0 = rabb + ((size_t)(b * NNN + n0 + w * 16 + quad * 4)) * NNN;
  const float* mk0 = mask + (size_t)b * NNN;
  int mtmax = qt + 1;

  for (int mt = 0; mt < mtmax; ++mt) {
    int m0 = mt * 64;
    __syncthreads();
#pragma unroll
    for (int t = 0; t < 4; ++t) {
      int lrow = w * 16 + t * 4 + (lane >> 4);
      int q = ((lane & 15) - lrow) & 15;
      __builtin_amdgcn_global_load_lds(
          (const __attribute__((address_space(1))) void*)(kg0 + (size_t)(m0 + lrow) * 2048 + q * 8),
          (__attribute__((address_space(3))) void*)(Ks + (w * 16 + t * 4) * 128),
          16, 0, 0);
    }
#pragma unroll
    for (int t = 0; t < 4; ++t) {
      int dv = w * 32 + t * 8 + (lane >> 3);
      int q = ((lane & 7) - dv) & 7;
      __builtin_amdgcn_global_load_lds(
          (const __attribute__((address_space(1))) void*)(vg0 + (size_t)dv * NNN + m0 + q * 8),
          (__attribute__((address_space(3))) void*)(Vs + (w * 32 + t * 8) * 64),
          16, 0, 0);
    }
    ushort rv[4][4];
#pragma unroll
    for (int tj = 0; tj < 4; ++tj)
#pragma unroll
      for (int r = 0; r < 4; ++r)
        rv[tj][r] = rb0[(size_t)r * NNN + m0 + tj * 16 + l16];
    __syncthreads();

    // ---- S = Q K^T ----
    f4_t sacc[4] = {};
#pragma unroll
    for (int kk = 0; kk < 4; ++kk) {
      bf8_t kf[4];
#pragma unroll
      for (int tj = 0; tj < 4; ++tj) {
        int lr = tj * 16 + l16;
        kf[tj] = *(const bf8_t*)&Ks[lr * 128 + (((kk * 4 + quad) + lr) & 15) * 8];
      }
#pragma unroll
      for (int tj = 0; tj < 4; ++tj)
        sacc[tj] = __builtin_amdgcn_mfma_f32_16x16x32_bf16(qf[kk], kf[tj],
                                                           sacc[tj], 0, 0, 0);
    }

    // ---- P = silu(S + rab)/N * causal * mask -> Ps ----
#pragma unroll
    for (int tj = 0; tj < 4; ++tj) {
      int m = tj * 16 + l16;
      int gj = m0 + m;
      float msc = mk0[gj] * (1.f / 1024.f);
#pragma unroll
      for (int r = 0; r < 4; ++r) {
        int q = w * 16 + quad * 4 + r;
        int gi = n0 + q;
        float z = sacc[tj][r] + bf2f(rv[tj][r]);
        float pp = z / (1.f + __expf(-z)) * msc;
        if (gj > gi) pp = 0.f;
        Ps[q * 64 + (((m >> 3) + q) & 7) * 8 + (m & 7)] = f2bf(pp);
      }
    }

    // ---- O += P V ----
#pragma unroll
    for (int kk = 0; kk < 2; ++kk) {
      bf8_t pf, vf[8];
      {
        int q = w * 16 + l16;
        pf = *(const bf8_t*)&Ps[q * 64 + (((kk * 4 + quad) + q) & 7) * 8];
      }
#pragma unroll
      for (int tj = 0; tj < 8; ++tj) {
        int dv = tj * 16 + l16;
        vf[tj] = *(const bf8_t*)&Vs[dv * 64 + (((kk * 4 + quad) + dv) & 7) * 8];
      }
#pragma unroll
      for (int tj = 0; tj < 8; ++tj)
        oacc[tj] = __builtin_amdgcn_mfma_f32_16x16x32_bf16(pf, vf[tj],
                                                           oacc[tj], 0, 0, 0);
    }
  }

  // ---- store O ----
#pragma unroll
  for (int tj = 0; tj < 8; ++tj) {
    int col = h * 128 + tj * 16 + l16;
#pragma unroll
    for (int r = 0; r < 4; ++r) {
      int gi = n0 + w * 16 + quad * 4 + r;
      o[((size_t)(b * NNN + gi)) * DDD + col] = oacc[tj][r];
    }
  }
}

// ---------------- pooling ---------------------------------------------------
__global__ __launch_bounds__(256) void row_stats_k(const float* __restrict__ xb,
                                                   const int* __restrict__ lenp,
                                                   float* __restrict__ invn) {
  __shared__ float sm[16];
  size_t row = blockIdx.x;
  if (((int)row & 1023) >= lenp[row >> 10]) return;
  int d = threadIdx.x * 4;
  float4 xv = *(const float4*)(xb + row * DDD + d);
  float ss = xv.x * xv.x + xv.y * xv.y + xv.z * xv.z + xv.w * xv.w;
  ss = block_reduce_sum(ss, sm);
  if (threadIdx.x == 0) invn[row] = 1.f / fmaxf(sqrtf(ss), 1e-12f);
}

__global__ __launch_bounds__(1024) void pool_partial_k(const float* __restrict__ xb,
                                                       const float* __restrict__ invn,
                                                       const int* __restrict__ lenp,
                                                       float* __restrict__ partial) {
  int b = blockIdx.x, c = blockIdx.y, d = threadIdx.x;
  int len = lenp[b];
  float s = 0.f;
  int nbeg = c * 64;
  int nend = min(nbeg + 64, len);
  for (int n = nbeg; n < nend; ++n) {
    size_t r = (size_t)b * NNN + n;
    s += xb[r * DDD + d] * invn[r];
  }
  partial[((size_t)b * 16 + c) * DDD + d] = s;
}

__global__ __launch_bounds__(1024) void pool_final_k(const float* __restrict__ xb,
                                                     const float* __restrict__ invn,
                                                     const float* __restrict__ partial,
                                                     const int* __restrict__ lenp,
                                                     float* __restrict__ out) {
  __shared__ float sm[16];
  int b = blockIdx.x, d = threadIdx.x;
  int len = lenp[b];
  float s = 0.f;
#pragma unroll
  for (int c = 0; c < 16; ++c) s += partial[((size_t)b * 16 + c) * DDD + d];
  float avg = s / (float)len;
  size_t lr = (size_t)b * NNN + (len - 1);
  float last = xb[lr * DDD + d] * invn[lr];
  float pooled = 0.5f * (last + avg);
  float ssq = block_reduce_sum(pooled * pooled, sm);
  out[(size_t)b * DDD + d] = pooled / fmaxf(sqrtf(ssq), 1e-12f);
}

// ---------------- launch ----------------------------------------------------
extern "C" void kernel_launch(void* const* d_in, const int* in_sizes, int n_in,
                              void* d_out, int out_size, void* d_ws, size_t ws_size,
                              hipStream_t stream) {
  const float* x      = (const float*)d_in[0];
  const int*   ts     = (const int*)d_in[1];
  const float* mask   = (const float*)d_in[2];
  const float* ln1_g  = (const float*)d_in[3];
  const float* ln1_b  = (const float*)d_in[4];
  const float* w_uvqk = (const float*)d_in[5];
  const float* b_uvqk = (const float*)d_in[6];
  const float* ln2_g  = (const float*)d_in[7];
  const float* ln2_b  = (const float*)d_in[8];
  const float* w_o    = (const float*)d_in[9];
  const float* b_o    = (const float*)d_in[10];
  const float* pos_w  = (const float*)d_in[11];
  const float* ts_w   = (const float*)d_in[12];
  float* out = (float*)d_out;

  float* ws = (float*)d_ws;
  const size_t SZ = (size_t)BB * NNN * DDD;            // 8M
  float* xb   = ws;                                     // 8M f
  float* buf1 = ws + SZ;                                // 8M f (o)
  float* ubuf = ws + 2 * SZ;                            // 8M f (u)
  ushort* hbf = (ushort*)(ws + 3 * SZ);                 // 8M bf16
  ushort* wuT = hbf + SZ;                               // 2 x 4096x1024
  ushort* woT = wuT + 2 * (size_t)DDD * CCC;            // 2 x 1024x1024
  ushort* qkb = woT + 2 * (size_t)DDD * DDD;            // 8192x2048
  ushort* vtb = qkb + (size_t)BB * NNN * 2048;          // 64x128x1024
  ushort* rabb = vtb + (size_t)BB * HHH * DVV * NNN;    // 8x1024x1024
  float* invn = (float*)(rabb + (size_t)BB * NNN * NNN);
  float* partial = invn + (size_t)BB * NNN;
  int* lenp = (int*)(partial + (size_t)BB * 16 * DDD);

  len_k<<<BB, 1024, 0, stream>>>(mask, lenp);

  for (int l = 0; l < 2; ++l) {
    wconv_k<<<dim3(DDD / 32, CCC / 32), 256, 0, stream>>>(
        w_uvqk + (size_t)l * DDD * CCC, wuT + (size_t)l * CCC * DDD, DDD, CCC);
    wconv_k<<<dim3(DDD / 32, DDD / 32), 256, 0, stream>>>(
        w_o + (size_t)l * DDD * DDD, woT + (size_t)l * DDD * DDD, DDD, DDD);
  }

  rab_k<<<dim3(8, 8, BB), 256, 0, stream>>>(ts, pos_w, ts_w, lenp, rabb);

  for (int l = 0; l < 2; ++l) {
    if (l == 0)
      ln_k<1><<<BB * NNN, 256, 0, stream>>>(x, ln1_g, ln1_b, nullptr, 0,
                                            lenp, xb, hbf);
    else
      ln_k<0><<<BB * NNN, 256, 0, stream>>>(xb, ln1_g + l * DDD,
                                            ln1_b + l * DDD, nullptr, 0,
                                            lenp, nullptr, hbf);
    gemm_bf_k<2><<<dim3(CCC / 128, BB * NNN / 128), 256, 0, stream>>>(
        hbf, wuT + (size_t)l * CCC * DDD, b_uvqk + (size_t)l * CCC,
        ubuf, qkb, vtb, lenp, DDD, CCC);
    attn_mfma_k<<<dim3(NNN / 64, HHH, BB), 256, 0, stream>>>(
        qkb, vtb, rabb, mask, lenp, buf1);
    ln_k<0><<<BB * NNN, 256, 0, stream>>>(buf1, ln2_g + l * DDD,
                                          ln2_b + l * DDD, ubuf, DDD,
                                          lenp, nullptr, hbf);
    gemm_bf_k<1><<<dim3(DDD / 128, BB * NNN / 128), 256, 0, stream>>>(
        hbf, woT + (size_t)l * DDD * DDD, b_o + (size_t)l * DDD,
        xb, nullptr, nullptr, lenp, DDD, DDD);
  }

  row_stats_k<<<BB * NNN, 256, 0, stream>>>(xb, lenp, invn);
  pool_partial_k<<<dim3(BB, 16), 1024, 0, stream>>>(xb, invn, lenp, partial);
  pool_final_k<<<BB, 1024, 0, stream>>>(xb, invn, partial, lenp, out);
}

// Round 7
// 631.519 us; speedup vs baseline: 5.1563x; 1.0610x over previous
//
#include <hip/hip_runtime.h>
#include <hip/hip_bf16.h>
#include <cstdint>
#include <cstddef>

// ---------------------------------------------------------------------------
// Round 7: BK=32 (r5 best) + LDS-transposed coalesced GEMM epilogue
// (u/q/k ushort4, w_o float4 RMW, V full-line transposed writes), u as bf16,
// wconv merged to one launch. K-loop staging/frag math identical to r5.
// ---------------------------------------------------------------------------

#define BB   8
#define NNN  1024
#define DDD  1024
#define HHH  8
#define DVV  128
#define CCC  4096
#define TBK  128

typedef __bf16 bf8_t  __attribute__((ext_vector_type(8)));
typedef float  f4_t   __attribute__((ext_vector_type(4)));
typedef ushort us8_t  __attribute__((ext_vector_type(8)));

__device__ __forceinline__ float bf2f(ushort u) {
  union { uint i; float f; } v; v.i = ((uint)u) << 16; return v.f;
}
__device__ __forceinline__ ushort f2bf(float f) {
  __hip_bfloat16 h = __float2bfloat16(f);
  return *(ushort*)&h;
}
__device__ __forceinline__ float silu(float z) {
  return z / (1.f + __expf(-z));
}

// ---------------- block reduce (blockDim 256 or 1024) ----------------------
__device__ __forceinline__ float block_reduce_sum(float v, float* sm) {
#pragma unroll
  for (int o = 32; o > 0; o >>= 1) v += __shfl_down(v, o, 64);
  int lane = threadIdx.x & 63;
  int wid  = threadIdx.x >> 6;
  __syncthreads();
  if (lane == 0) sm[wid] = v;
  __syncthreads();
  int nw = blockDim.x >> 6;
  float r = (threadIdx.x < nw) ? sm[threadIdx.x] : 0.f;
#pragma unroll
  for (int o = 8; o > 0; o >>= 1) r += __shfl_down(r, o, 64);
  if (threadIdx.x == 0) sm[0] = r;
  __syncthreads();
  return sm[0];
}

// ---------------- len[b] ----------------------------------------------------
__global__ __launch_bounds__(1024) void len_k(const float* __restrict__ mask,
                                              int* __restrict__ lenp) {
  __shared__ float sm[16];
  int b = blockIdx.x;
  float m = mask[(size_t)b * NNN + threadIdx.x];
  float s = block_reduce_sum(m, sm);
  if (threadIdx.x == 0) lenp[b] = (int)(s + 0.5f);
}

// ---------------- all weight transposes in one launch -----------------------
// grid (32, 160, 2): by<128 -> w_uvqk tile, else w_o tile.
__global__ __launch_bounds__(256) void wconv_all_k(const float* __restrict__ w_uvqk,
                                                   const float* __restrict__ w_o,
                                                   ushort* __restrict__ wuT,
                                                   ushort* __restrict__ woT) {
  __shared__ float t[32][33];
  int l = blockIdx.z;
  int k0 = blockIdx.x * 32;
  int by = blockIdx.y;
  const float* W; ushort* Wt; int Nn, n0;
  if (by < 128) {
    W = w_uvqk + (size_t)l * DDD * CCC; Wt = wuT + (size_t)l * CCC * DDD;
    Nn = CCC; n0 = by * 32;
  } else {
    W = w_o + (size_t)l * DDD * DDD; Wt = woT + (size_t)l * DDD * DDD;
    Nn = DDD; n0 = (by - 128) * 32;
  }
  int tx = threadIdx.x & 31, ty = threadIdx.x >> 5;
  for (int r = ty; r < 32; r += 8)
    t[r][tx] = W[(size_t)(k0 + r) * Nn + n0 + tx];
  __syncthreads();
  for (int r = ty; r < 32; r += 8)
    Wt[(size_t)(n0 + r) * 1024 + k0 + tx] = f2bf(t[tx][r]);
}

// ---------------- rab precompute -------------------------------------------
__global__ __launch_bounds__(256) void rab_k(const int* __restrict__ ts,
                                             const float* __restrict__ pos_w,
                                             const float* __restrict__ ts_w,
                                             const int* __restrict__ lenp,
                                             ushort* __restrict__ rabb) {
  int jt = blockIdx.x, it = blockIdx.y, b = blockIdx.z;
  if (jt > it) return;
  int len = lenp[b];
  if (it * 128 >= len || jt * 128 >= len) return;
  int j = jt * 128 + (threadIdx.x & 127);
  int half = threadIdx.x >> 7;
  int tsj = ts[(size_t)b * NNN + j];
  for (int rr = 0; rr < 64; ++rr) {
    int i = it * 128 + rr * 2 + half;
    int ii = i + 1; if (ii > NNN - 1) ii = NNN - 1;
    int tsi = ts[(size_t)b * NNN + ii];
    float af = fabsf((float)(tsi - tsj));
    af = fmaxf(af, 1.f);
    int bkt = (int)__log2f(af);
    bkt = min(max(bkt, 0), TBK);
    float rab = pos_w[i - j + NNN - 1] + ts_w[bkt];
    rabb[((size_t)b * NNN + i) * NNN + j] = f2bf(rab);
  }
}

// ---------------- LayerNorm. FIRST=1: also copy x -> xb. umat: bf16 u -------
template <int FIRST>
__global__ __launch_bounds__(256) void ln_k(const float* __restrict__ X,
                                            const float* __restrict__ g,
                                            const float* __restrict__ bsh,
                                            const ushort* __restrict__ umat,
                                            const int* __restrict__ lenp,
                                            float* __restrict__ xb,
                                            ushort* __restrict__ Y) {
  __shared__ float sm[16];
  size_t row = blockIdx.x;
  if (((int)row & 1023) >= lenp[row >> 10]) return;
  const float* xr = X + row * DDD;
  int d = threadIdx.x * 4;
  float4 xv = *(const float4*)(xr + d);
  if (FIRST) *(float4*)(xb + row * DDD + d) = xv;
  float s = xv.x + xv.y + xv.z + xv.w;
  s = block_reduce_sum(s, sm);
  float mu = s * (1.f / 1024.f);
  float d0 = xv.x - mu, d1 = xv.y - mu, d2 = xv.z - mu, d3 = xv.w - mu;
  float ss = d0 * d0 + d1 * d1 + d2 * d2 + d3 * d3;
  ss = block_reduce_sum(ss, sm);
  float rs = rsqrtf(ss * (1.f / 1024.f) + 1e-6f);
  float y0 = d0 * rs * g[d + 0] + bsh[d + 0];
  float y1 = d1 * rs * g[d + 1] + bsh[d + 1];
  float y2 = d2 * rs * g[d + 2] + bsh[d + 2];
  float y3 = d3 * rs * g[d + 3] + bsh[d + 3];
  if (umat != nullptr) {
    ushort4 uv = *(const ushort4*)(umat + row * 1024 + d);
    y0 *= bf2f(uv.x); y1 *= bf2f(uv.y); y2 *= bf2f(uv.z); y3 *= bf2f(uv.w);
  }
  ushort tmp[4] = { f2bf(y0), f2bf(y1), f2bf(y2), f2bf(y3) };
  *(uint2*)(Y + row * DDD + d) = *(uint2*)tmp;
}

// ---------------- bf16 MFMA GEMM, BK=32, LDS-transposed epilogue ------------
// MODE 1: C(fp32) += z + bias   (w_o GEMM, Nn=1024), coalesced float4 RMW.
// MODE 2: uvqk split by 1024-col region:
//   region 0: u  -> U bf16 (stride 1024), silu
//   region 1: v  -> Vt[b,h,dv,n] bf16 transposed (full-line writes), silu
//   region 2/3: q,k -> Qk bf16 (stride 2048), silu
template <int MODE>
__global__ __launch_bounds__(256) void gemm_bf_k(const ushort* __restrict__ A,
                                                 const ushort* __restrict__ Bt,
                                                 const float* __restrict__ bias,
                                                 float* __restrict__ C,
                                                 ushort* __restrict__ U,
                                                 ushort* __restrict__ Qk,
                                                 ushort* __restrict__ Vt,
                                                 const int* __restrict__ lenp,
                                                 int K, int Nn) {
  __shared__ alignas(16) char smem[64 * 132 * 4];   // 33792 B
  ushort* As = (ushort*)smem;          // 128 x 32
  ushort* Bs = As + 128 * 32;          // 128 x 32
  float*  eps = (float*)smem;          // 64 x 132 (epilogue scratch)

  int m0 = blockIdx.y * 128, n0 = blockIdx.x * 128;
  if ((m0 & 1023) >= lenp[m0 >> 10]) return;
  int tid = threadIdx.x;
  int wave = tid >> 6, lane = tid & 63;
  int quad = lane >> 4, l16 = lane & 15;
  int wm = wave >> 1, wn = wave & 1;

  f4_t acc[4][4] = {};

  int r_l = tid >> 2;
  int p   = tid & 3;

  for (int k0 = 0; k0 < K; k0 += 32) {
    __syncthreads();
#pragma unroll
    for (int g = 0; g < 2; ++g) {
      int row = g * 64 + r_l;
      int q = (p - (row >> 1)) & 3;
      __builtin_amdgcn_global_load_lds(
          (const __attribute__((address_space(1))) void*)(A + (size_t)(m0 + row) * K + k0 + q * 8),
          (__attribute__((address_space(3))) void*)(As + (g * 64 + wave * 16) * 32),
          16, 0, 0);
      __builtin_amdgcn_global_load_lds(
          (const __attribute__((address_space(1))) void*)(Bt + (size_t)(n0 + row) * K + k0 + q * 8),
          (__attribute__((address_space(3))) void*)(Bs + (g * 64 + wave * 16) * 32),
          16, 0, 0);
    }
    __syncthreads();

    bf8_t af[4], bfr[4];
#pragma unroll
    for (int t = 0; t < 4; ++t) {
      int row = wm * 64 + t * 16 + l16;
      af[t] = *(const bf8_t*)&As[row * 32 + ((quad + (row >> 1)) & 3) * 8];
      int col = wn * 64 + t * 16 + l16;
      bfr[t] = *(const bf8_t*)&Bs[col * 32 + ((quad + (col >> 1)) & 3) * 8];
    }
#pragma unroll
    for (int i = 0; i < 4; ++i)
#pragma unroll
      for (int j = 0; j < 4; ++j)
        acc[i][j] = __builtin_amdgcn_mfma_f32_16x16x32_bf16(af[i], bfr[j],
                                                            acc[i][j], 0, 0, 0);
  }

  // ---- epilogue: two phases (m-halves), LDS transpose then coalesced store
  int region = (MODE == 2) ? (n0 >> 10) : -1;
#pragma unroll
  for (int ph = 0; ph < 2; ++ph) {
    __syncthreads();   // frag reads / previous phase reads done
    if (wm == ph) {
#pragma unroll
      for (int i = 0; i < 4; ++i)
#pragma unroll
        for (int j = 0; j < 4; ++j)
#pragma unroll
          for (int r = 0; r < 4; ++r)
            eps[(i * 16 + quad * 4 + r) * 132 + wn * 64 + j * 16 + l16] =
                acc[i][j][r];
    }
    __syncthreads();

    int mbase = m0 + ph * 64;
    if (MODE == 1 || region == 0 || region >= 2) {
      int row = tid >> 2;
      int c0 = (tid & 3) * 4;
      int gr = mbase + row;
      const float* er = eps + row * 132;
#pragma unroll
      for (int s = 0; s < 8; ++s) {
        int col = c0 + s * 16;
        float4 b4 = *(const float4*)(bias + n0 + col);
        float z0 = er[col + 0] + b4.x;
        float z1 = er[col + 1] + b4.y;
        float z2 = er[col + 2] + b4.z;
        float z3 = er[col + 3] + b4.w;
        if (MODE == 1) {
          float* cp = C + (size_t)gr * Nn + n0 + col;
          float4 c4 = *(const float4*)cp;
          c4.x += z0; c4.y += z1; c4.z += z2; c4.w += z3;
          *(float4*)cp = c4;
        } else {
          ushort4 pk;
          pk.x = f2bf(silu(z0)); pk.y = f2bf(silu(z1));
          pk.z = f2bf(silu(z2)); pk.w = f2bf(silu(z3));
          if (region == 0)
            *(ushort4*)(U + (size_t)gr * 1024 + n0 + col) = pk;
          else
            *(ushort4*)(Qk + (size_t)gr * 2048 + (n0 + col - 2048)) = pk;
        }
      }
    } else {
      // region 1: V -> Vt transposed. thread: one column, 32 rows.
      int col = tid & 127;
      int half = tid >> 7;
      float bz = bias[n0 + col];
      int hb = (n0 >> 7) & 7;
      ushort* vrow = Vt + (((size_t)((m0 >> 10) * 8 + hb)) * 128 + col) * NNN +
                     (mbase & 1023) + half * 32;
#pragma unroll
      for (int g = 0; g < 4; ++g) {
        us8_t pk;
#pragma unroll
        for (int e = 0; e < 8; ++e) {
          int r = half * 32 + g * 8 + e;
          pk[e] = f2bf(silu(eps[r * 132 + col] + bz));
        }
        *(us8_t*)(vrow + g * 8) = pk;
      }
    }
  }
}

// ---------------- MFMA flash attention --------------------------------------
__global__ __launch_bounds__(256, 4) void attn_mfma_k(
    const ushort* __restrict__ qk, const ushort* __restrict__ vt,
    const ushort* __restrict__ rabb, const float* __restrict__ mask,
    const int* __restrict__ lenp, float* __restrict__ o) {
  __shared__ alignas(16) ushort Ks[64 * 128];   // 16 KB
  __shared__ alignas(16) ushort Vs[128 * 64];   // 16 KB
  __shared__ alignas(16) ushort Ps[64 * 64];    // 8 KB
  int h = blockIdx.y, b = blockIdx.z;
  int qt = ((int)blockIdx.x + (int)blockIdx.y + 2 * (int)blockIdx.z) & 15;
  int n0 = qt * 64;
  if (n0 >= lenp[b]) return;
  int tid = threadIdx.x, w = tid >> 6, lane = tid & 63;
  int quad = lane >> 4, l16 = lane & 15;

  const ushort* qg0 = qk + ((size_t)(b * NNN + n0)) * 2048 + h * 128;
#pragma unroll
  for (int t = 0; t < 4; ++t) {
    int lrow = w * 16 + t * 4 + (lane >> 4);
    int q = ((lane & 15) - lrow) & 15;
    __builtin_amdgcn_global_load_lds(
        (const __attribute__((address_space(1))) void*)(qg0 + (size_t)lrow * 2048 + q * 8),
        (__attribute__((address_space(3))) void*)(Ks + (w * 16 + t * 4) * 128),
        16, 0, 0);
  }
  __syncthreads();
  bf8_t qf[4];
  {
    int lr = w * 16 + l16;
#pragma unroll
    for (int kk = 0; kk < 4; ++kk)
      qf[kk] = *(const bf8_t*)&Ks[lr * 128 + (((kk * 4 + quad) + lr) & 15) * 8];
  }

  f4_t oacc[8] = {};
  const ushort* kg0 = qk + (size_t)b * NNN * 2048 + 1024 + h * 128;
  const ushort* vg0 = vt + (size_t)(b * 8 + h) * 128 * NNN;
  const ushort* rb0 = rabb + ((size_t)(b * NNN + n0 + w * 16 + quad * 4)) * NNN;
  const float* mk0 = mask + (size_t)b * NNN;
  int mtmax = qt + 1;

  for (int mt = 0; mt < mtmax; ++mt) {
    int m0 = mt * 64;
    __syncthreads();
#pragma unroll
    for (int t = 0; t < 4; ++t) {
      int lrow = w * 16 + t * 4 + (lane >> 4);
      int q = ((lane & 15) - lrow) & 15;
      __builtin_amdgcn_global_load_lds(
          (const __attribute__((address_space(1))) void*)(kg0 + (size_t)(m0 + lrow) * 2048 + q * 8),
          (__attribute__((address_space(3))) void*)(Ks + (w * 16 + t * 4) * 128),
          16, 0, 0);
    }
#pragma unroll
    for (int t = 0; t < 4; ++t) {
      int dv = w * 32 + t * 8 + (lane >> 3);
      int q = ((lane & 7) - dv) & 7;
      __builtin_amdgcn_global_load_lds(
          (const __attribute__((address_space(1))) void*)(vg0 + (size_t)dv * NNN + m0 + q * 8),
          (__attribute__((address_space(3))) void*)(Vs + (w * 32 + t * 8) * 64),
          16, 0, 0);
    }
    ushort rv[4][4];
#pragma unroll
    for (int tj = 0; tj < 4; ++tj)
#pragma unroll
      for (int r = 0; r < 4; ++r)
        rv[tj][r] = rb0[(size_t)r * NNN + m0 + tj * 16 + l16];
    __syncthreads();

    f4_t sacc[4] = {};
#pragma unroll
    for (int kk = 0; kk < 4; ++kk) {
      bf8_t kf[4];
#pragma unroll
      for (int tj = 0; tj < 4; ++tj) {
        int lr = tj * 16 + l16;
        kf[tj] = *(const bf8_t*)&Ks[lr * 128 + (((kk * 4 + quad) + lr) & 15) * 8];
      }
#pragma unroll
      for (int tj = 0; tj < 4; ++tj)
        sacc[tj] = __builtin_amdgcn_mfma_f32_16x16x32_bf16(qf[kk], kf[tj],
                                                           sacc[tj], 0, 0, 0);
    }

#pragma unroll
    for (int tj = 0; tj < 4; ++tj) {
      int m = tj * 16 + l16;
      int gj = m0 + m;
      float msc = mk0[gj] * (1.f / 1024.f);
#pragma unroll
      for (int r = 0; r < 4; ++r) {
        int q = w * 16 + quad * 4 + r;
        int gi = n0 + q;
        float z = sacc[tj][r] + bf2f(rv[tj][r]);
        float pp = silu(z) * msc;
        if (gj > gi) pp = 0.f;
        Ps[q * 64 + (((m >> 3) + q) & 7) * 8 + (m & 7)] = f2bf(pp);
      }
    }

#pragma unroll
    for (int kk = 0; kk < 2; ++kk) {
      bf8_t pf, vf[8];
      {
        int q = w * 16 + l16;
        pf = *(const bf8_t*)&Ps[q * 64 + (((kk * 4 + quad) + q) & 7) * 8];
      }
#pragma unroll
      for (int tj = 0; tj < 8; ++tj) {
        int dv = tj * 16 + l16;
        vf[tj] = *(const bf8_t*)&Vs[dv * 64 + (((kk * 4 + quad) + dv) & 7) * 8];
      }
#pragma unroll
      for (int tj = 0; tj < 8; ++tj)
        oacc[tj] = __builtin_amdgcn_mfma_f32_16x16x32_bf16(pf, vf[tj],
                                                           oacc[tj], 0, 0, 0);
    }
  }

#pragma unroll
  for (int tj = 0; tj < 8; ++tj) {
    int col = h * 128 + tj * 16 + l16;
#pragma unroll
    for (int r = 0; r < 4; ++r) {
      int gi = n0 + w * 16 + quad * 4 + r;
      o[((size_t)(b * NNN + gi)) * DDD + col] = oacc[tj][r];
    }
  }
}

// ---------------- pooling ---------------------------------------------------
__global__ __launch_bounds__(256) void row_stats_k(const float* __restrict__ xb,
                                                   const int* __restrict__ lenp,
                                                   float* __restrict__ invn) {
  __shared__ float sm[16];
  size_t row = blockIdx.x;
  if (((int)row & 1023) >= lenp[row >> 10]) return;
  int d = threadIdx.x * 4;
  float4 xv = *(const float4*)(xb + row * DDD + d);
  float ss = xv.x * xv.x + xv.y * xv.y + xv.z * xv.z + xv.w * xv.w;
  ss = block_reduce_sum(ss, sm);
  if (threadIdx.x == 0) invn[row] = 1.f / fmaxf(sqrtf(ss), 1e-12f);
}

__global__ __launch_bounds__(1024) void pool_partial_k(const float* __restrict__ xb,
                                                       const float* __restrict__ invn,
                                                       const int* __restrict__ lenp,
                                                       float* __restrict__ partial) {
  int b = blockIdx.x, c = blockIdx.y, d = threadIdx.x;
  int len = lenp[b];
  float s = 0.f;
  int nbeg = c * 64;
  int nend = min(nbeg + 64, len);
  for (int n = nbeg; n < nend; ++n) {
    size_t r = (size_t)b * NNN + n;
    s += xb[r * DDD + d] * invn[r];
  }
  partial[((size_t)b * 16 + c) * DDD + d] = s;
}

__global__ __launch_bounds__(1024) void pool_final_k(const float* __restrict__ xb,
                                                     const float* __restrict__ invn,
                                                     const float* __restrict__ partial,
                                                     const int* __restrict__ lenp,
                                                     float* __restrict__ out) {
  __shared__ float sm[16];
  int b = blockIdx.x, d = threadIdx.x;
  int len = lenp[b];
  float s = 0.f;
#pragma unroll
  for (int c = 0; c < 16; ++c) s += partial[((size_t)b * 16 + c) * DDD + d];
  float avg = s / (float)len;
  size_t lr = (size_t)b * NNN + (len - 1);
  float last = xb[lr * DDD + d] * invn[lr];
  float pooled = 0.5f * (last + avg);
  float ssq = block_reduce_sum(pooled * pooled, sm);
  out[(size_t)b * DDD + d] = pooled / fmaxf(sqrtf(ssq), 1e-12f);
}

// ---------------- launch ----------------------------------------------------
extern "C" void kernel_launch(void* const* d_in, const int* in_sizes, int n_in,
                              void* d_out, int out_size, void* d_ws, size_t ws_size,
                              hipStream_t stream) {
  const float* x      = (const float*)d_in[0];
  const int*   ts     = (const int*)d_in[1];
  const float* mask   = (const float*)d_in[2];
  const float* ln1_g  = (const float*)d_in[3];
  const float* ln1_b  = (const float*)d_in[4];
  const float* w_uvqk = (const float*)d_in[5];
  const float* b_uvqk = (const float*)d_in[6];
  const float* ln2_g  = (const float*)d_in[7];
  const float* ln2_b  = (const float*)d_in[8];
  const float* w_o    = (const float*)d_in[9];
  const float* b_o    = (const float*)d_in[10];
  const float* pos_w  = (const float*)d_in[11];
  const float* ts_w   = (const float*)d_in[12];
  float* out = (float*)d_out;

  float* ws = (float*)d_ws;
  const size_t SZ = (size_t)BB * NNN * DDD;            // 8M
  float* xb   = ws;                                     // 8M f
  float* buf1 = ws + SZ;                                // 8M f (o)
  ushort* ubuf = (ushort*)(ws + 2 * SZ);                // 8192x1024 bf16 (u)
  ushort* hbf = (ushort*)(ws + 3 * SZ);                 // 8M bf16
  ushort* wuT = hbf + SZ;                               // 2 x 4096x1024
  ushort* woT = wuT + 2 * (size_t)DDD * CCC;            // 2 x 1024x1024
  ushort* qkb = woT + 2 * (size_t)DDD * DDD;            // 8192x2048
  ushort* vtb = qkb + (size_t)BB * NNN * 2048;          // 64x128x1024
  ushort* rabb = vtb + (size_t)BB * HHH * DVV * NNN;    // 8x1024x1024
  float* invn = (float*)(rabb + (size_t)BB * NNN * NNN);
  float* partial = invn + (size_t)BB * NNN;
  int* lenp = (int*)(partial + (size_t)BB * 16 * DDD);

  len_k<<<BB, 1024, 0, stream>>>(mask, lenp);
  wconv_all_k<<<dim3(32, 160, 2), 256, 0, stream>>>(w_uvqk, w_o, wuT, woT);
  rab_k<<<dim3(8, 8, BB), 256, 0, stream>>>(ts, pos_w, ts_w, lenp, rabb);

  for (int l = 0; l < 2; ++l) {
    if (l == 0)
      ln_k<1><<<BB * NNN, 256, 0, stream>>>(x, ln1_g, ln1_b, nullptr,
                                            lenp, xb, hbf);
    else
      ln_k<0><<<BB * NNN, 256, 0, stream>>>(xb, ln1_g + l * DDD,
                                            ln1_b + l * DDD, nullptr,
                                            lenp, nullptr, hbf);
    gemm_bf_k<2><<<dim3(CCC / 128, BB * NNN / 128), 256, 0, stream>>>(
        hbf, wuT + (size_t)l * CCC * DDD, b_uvqk + (size_t)l * CCC,
        nullptr, ubuf, qkb, vtb, lenp, DDD, CCC);
    attn_mfma_k<<<dim3(NNN / 64, HHH, BB), 256, 0, stream>>>(
        qkb, vtb, rabb, mask, lenp, buf1);
    ln_k<0><<<BB * NNN, 256, 0, stream>>>(buf1, ln2_g + l * DDD,
                                          ln2_b + l * DDD, ubuf,
                                          lenp, nullptr, hbf);
    gemm_bf_k<1><<<dim3(DDD / 128, BB * NNN / 128), 256, 0, stream>>>(
        hbf, woT + (size_t)l * DDD * DDD, b_o + (size_t)l * DDD,
        xb, nullptr, nullptr, nullptr, lenp, DDD, DDD);
  }

  row_stats_k<<<BB * NNN, 256, 0, stream>>>(xb, lenp, invn);
  pool_partial_k<<<dim3(BB, 16), 1024, 0, stream>>>(xb, invn, lenp, partial);
  pool_final_k<<<BB, 1024, 0, stream>>>(xb, invn, partial, lenp, out);
}